// Round 1
// baseline (2973.272 us; speedup 1.0000x reference)
//
#include <hip/hip_runtime.h>
#include <hip/hip_bf16.h>
#include <math.h>

#define S_LEN 2048
#define HID_DIM 2048
#define NH 32
#define NOPE 128
#define ROPE_D 64
#define QKD 192           // NOPE + ROPE
#define VD 128
#define KV_RANK 512
#define SW 128
#define NQK (NH*QKD)      // 6144
#define CKV_N (KV_RANK+ROPE_D) // 576
#define KVN (NH*(NOPE+VD))     // 8192
#define OUT_HID 2048
#define ATT_SCALE 0.07216878364870323f  // 192^-0.5
#define NEG_INF (-1e30f)

// ---------------------------------------------------------------------------
// Generic tiled fp32 GEMM: C[M,N] = A[M,K] (lda) @ B[K,N] (ldb) + bias
// All M multiples of 64, N multiples of 64, K multiples of 16 in this problem,
// so no bounds guards (asserted by launch params below).
// ---------------------------------------------------------------------------
#define TM 64
#define TN 64
#define TK 16

__global__ __launch_bounds__(256)
void gemm_f32(const float* __restrict__ A, int lda,
              const float* __restrict__ B, int ldb,
              const float* __restrict__ bias,
              float* __restrict__ C, int ldc,
              int K)
{
    __shared__ float As[TK][TM + 1];   // +1 pad: breaks 16-way write conflict
    __shared__ float Bs[TK][TN];

    const int tid = threadIdx.x;       // 0..255
    const int tx = tid & 15;           // 16 col-groups
    const int ty = tid >> 4;           // 16 row-groups
    const int row0 = blockIdx.y * TM;
    const int col0 = blockIdx.x * TN;

    float acc[4][4] = {};

    for (int k0 = 0; k0 < K; k0 += TK) {
        // A tile: 64 rows x 16 k -> As transposed. 1024 elems, 4/thread.
        #pragma unroll
        for (int l = 0; l < 4; ++l) {
            int e = tid + l * 256;
            int ar = e >> 4, ak = e & 15;
            As[ak][ar] = A[(size_t)(row0 + ar) * lda + k0 + ak];
        }
        // B tile: 16 k x 64 cols. coalesced along cols.
        #pragma unroll
        for (int l = 0; l < 4; ++l) {
            int e = tid + l * 256;
            int bk = e >> 6, bc = e & 63;
            Bs[bk][bc] = B[(size_t)(k0 + bk) * ldb + col0 + bc];
        }
        __syncthreads();
        #pragma unroll
        for (int kk = 0; kk < TK; ++kk) {
            float a[4], b[4];
            #pragma unroll
            for (int mi = 0; mi < 4; ++mi) a[mi] = As[kk][ty * 4 + mi];
            #pragma unroll
            for (int ni = 0; ni < 4; ++ni) b[ni] = Bs[kk][tx * 4 + ni];
            #pragma unroll
            for (int mi = 0; mi < 4; ++mi)
                #pragma unroll
                for (int ni = 0; ni < 4; ++ni)
                    acc[mi][ni] = fmaf(a[mi], b[ni], acc[mi][ni]);
        }
        __syncthreads();
    }

    #pragma unroll
    for (int mi = 0; mi < 4; ++mi) {
        int r = row0 + ty * 4 + mi;
        #pragma unroll
        for (int ni = 0; ni < 4; ++ni) {
            int c = col0 + tx * 4 + ni;
            float v = acc[mi][ni];
            if (bias) v += bias[c];
            C[(size_t)r * ldc + c] = v;
        }
    }
}

// ---------------------------------------------------------------------------
// RoPE in-place on q_rope (all 32 heads) and k_rope (tail of ckv).
// rotate_half: new[d]    = x[d]*cos[d]    - x[d+32]*sin[d]       (d < 32)
//              new[d+32] = x[d+32]*cos[d+32] + x[d]*sin[d+32]
// grid = S, block = 256. (NH+1)*32 = 1056 pairs per token.
// ---------------------------------------------------------------------------
__global__ __launch_bounds__(256)
void rope_kernel(float* __restrict__ q, float* __restrict__ ckv,
                 const float* __restrict__ cosb, const float* __restrict__ sinb)
{
    const int s = blockIdx.x;
    const float* c  = cosb + (size_t)s * ROPE_D;
    const float* si = sinb + (size_t)s * ROPE_D;
    for (int idx = threadIdx.x; idx < (NH + 1) * 32; idx += 256) {
        int hh = idx >> 5;
        int d  = idx & 31;
        float* base = (hh < NH) ? (q + (size_t)s * NQK + hh * QKD + NOPE)
                                : (ckv + (size_t)s * CKV_N + KV_RANK);
        float x0 = base[d];
        float x1 = base[d + 32];
        base[d]      = x0 * c[d]      - x1 * si[d];
        base[d + 32] = x1 * c[d + 32] + x0 * si[d + 32];
    }
}

// ---------------------------------------------------------------------------
// Sliding-window causal attention with sink.
// One block (128 threads) per (query i, head h).
//   phase 1: thread t computes logit for key j = j0 + t (t < nk)
//   phase 2: block softmax incl. sink in max & denominator
//   phase 3: thread t = output dim d, accumulates sum_j p[j] * v[j][d]
// ---------------------------------------------------------------------------
__global__ __launch_bounds__(128)
void attn_kernel(const float* __restrict__ q, const float* __restrict__ kv,
                 const float* __restrict__ ckv, const float* __restrict__ sinks,
                 float* __restrict__ out)
{
    const int i = blockIdx.x;   // query position
    const int h = blockIdx.y;   // head
    const int t = threadIdx.x;  // 0..127

    __shared__ float qs[QKD];
    __shared__ float red[128];
    __shared__ float p[SW];

    for (int d = t; d < QKD; d += 128)
        qs[d] = q[(size_t)i * NQK + h * QKD + d];
    __syncthreads();

    const int j0 = (i >= SW - 1) ? (i - SW + 1) : 0;
    const int nk = i - j0 + 1;   // 1..128

    float logit = NEG_INF;
    if (t < nk) {
        const int j = j0 + t;
        const float* kn = kv  + (size_t)j * KVN + h * (NOPE + VD);
        const float* kr = ckv + (size_t)j * CKV_N + KV_RANK;
        float s = 0.f;
        #pragma unroll 8
        for (int d = 0; d < NOPE; ++d) s = fmaf(qs[d], kn[d], s);
        #pragma unroll 8
        for (int d = 0; d < ROPE_D; ++d) s = fmaf(qs[NOPE + d], kr[d], s);
        logit = s * ATT_SCALE;
    }

    const float sink = sinks[h];

    // block max
    red[t] = logit;
    __syncthreads();
    for (int off = 64; off > 0; off >>= 1) {
        if (t < off) red[t] = fmaxf(red[t], red[t + off]);
        __syncthreads();
    }
    const float m = fmaxf(red[0], sink);
    __syncthreads();

    // block sum of exp
    float e = (t < nk) ? __expf(logit - m) : 0.f;
    red[t] = e;
    __syncthreads();
    for (int off = 64; off > 0; off >>= 1) {
        if (t < off) red[t] += red[t + off];
        __syncthreads();
    }
    const float denom = red[0] + __expf(sink - m);
    p[t] = e / denom;
    __syncthreads();

    // P @ V : thread t = output dim
    float acc = 0.f;
    const float* vbase = kv + (size_t)j0 * KVN + h * (NOPE + VD) + NOPE + t;
    #pragma unroll 4
    for (int jj = 0; jj < nk; ++jj)
        acc = fmaf(p[jj], vbase[(size_t)jj * KVN], acc);
    out[(size_t)i * (NH * VD) + h * VD + t] = acc;
}

// ---------------------------------------------------------------------------
extern "C" void kernel_launch(void* const* d_in, const int* in_sizes, int n_in,
                              void* d_out, int out_size, void* d_ws, size_t ws_size,
                              hipStream_t stream) {
    const float* hidden = (const float*)d_in[0];
    const float* cosb   = (const float*)d_in[1];
    const float* sinb   = (const float*)d_in[2];
    const float* Wq     = (const float*)d_in[3];
    const float* bq     = (const float*)d_in[4];
    const float* Wkva   = (const float*)d_in[5];
    const float* bkva   = (const float*)d_in[6];
    const float* Wkvb   = (const float*)d_in[7];
    const float* Wo     = (const float*)d_in[8];
    const float* bo     = (const float*)d_in[9];
    const float* sinks  = (const float*)d_in[10];
    float* out = (float*)d_out;

    // workspace carve-up (fp32): 50.3 + 4.7 + 67.1 + 33.6 = 155.7 MB
    float* q        = (float*)d_ws;                 // [S][NH*QKD]
    float* ckv      = q   + (size_t)S_LEN * NQK;    // [S][576]
    float* kv       = ckv + (size_t)S_LEN * CKV_N;  // [S][NH*256]
    float* attn_out = kv  + (size_t)S_LEN * KVN;    // [S][NH*VD]

    const dim3 blk(256);

    // q = hidden @ Wq + bq            (2048 x 6144, K=2048)
    gemm_f32<<<dim3(NQK / TN, S_LEN / TM), blk, 0, stream>>>(
        hidden, HID_DIM, Wq, NQK, bq, q, NQK, HID_DIM);

    // ckv = hidden @ Wkva + bkva      (2048 x 576, K=2048)
    gemm_f32<<<dim3(CKV_N / TN, S_LEN / TM), blk, 0, stream>>>(
        hidden, HID_DIM, Wkva, CKV_N, bkva, ckv, CKV_N, HID_DIM);

    // RoPE on q_rope (per head) and k_rope (tail of ckv)
    rope_kernel<<<S_LEN, 256, 0, stream>>>(q, ckv, cosb, sinb);

    // kv = ckv[:, :512] @ Wkvb        (2048 x 8192, K=512, lda=576)
    gemm_f32<<<dim3(KVN / TN, S_LEN / TM), blk, 0, stream>>>(
        ckv, CKV_N, Wkvb, KVN, nullptr, kv, KVN, KV_RANK);

    // sliding-window attention with sink
    attn_kernel<<<dim3(S_LEN, NH), 128, 0, stream>>>(q, kv, ckv, sinks, attn_out);

    // out = attn_out @ Wo + bo        (2048 x 2048, K=4096)
    gemm_f32<<<dim3(OUT_HID / TN, S_LEN / TM), blk, 0, stream>>>(
        attn_out, NH * VD, Wo, OUT_HID, bo, out, OUT_HID, NH * VD);
}

// Round 2
// 2333.534 us; speedup vs baseline: 1.2741x; 1.2741x over previous
//
#include <hip/hip_runtime.h>
#include <hip/hip_bf16.h>
#include <math.h>

#define S_LEN 2048
#define HID_DIM 2048
#define NH 32
#define NOPE 128
#define ROPE_D 64
#define QKD 192           // NOPE + ROPE
#define VD 128
#define KV_RANK 512
#define SW 128
#define NQK (NH*QKD)      // 6144
#define CKV_N (KV_RANK+ROPE_D) // 576
#define KVN (NH*(NOPE+VD))     // 8192
#define OUT_HID 2048
#define ATT_SCALE 0.07216878364870323f  // 192^-0.5
#define NEG_INF (-1e30f)

// ---------------------------------------------------------------------------
// Generic tiled fp32 GEMM: C[M,N] = A[M,K] (lda) @ B[K,N] (ldb) + bias
// ---------------------------------------------------------------------------
#define TM 64
#define TN 64
#define TK 16

__global__ __launch_bounds__(256)
void gemm_f32(const float* __restrict__ A, int lda,
              const float* __restrict__ B, int ldb,
              const float* __restrict__ bias,
              float* __restrict__ C, int ldc,
              int K)
{
    __shared__ float As[TK][TM + 1];
    __shared__ float Bs[TK][TN];

    const int tid = threadIdx.x;
    const int tx = tid & 15;
    const int ty = tid >> 4;
    const int row0 = blockIdx.y * TM;
    const int col0 = blockIdx.x * TN;

    float acc[4][4] = {};

    for (int k0 = 0; k0 < K; k0 += TK) {
        #pragma unroll
        for (int l = 0; l < 4; ++l) {
            int e = tid + l * 256;
            int ar = e >> 4, ak = e & 15;
            As[ak][ar] = A[(size_t)(row0 + ar) * lda + k0 + ak];
        }
        #pragma unroll
        for (int l = 0; l < 4; ++l) {
            int e = tid + l * 256;
            int bk = e >> 6, bc = e & 63;
            Bs[bk][bc] = B[(size_t)(k0 + bk) * ldb + col0 + bc];
        }
        __syncthreads();
        #pragma unroll
        for (int kk = 0; kk < TK; ++kk) {
            float a[4], b[4];
            #pragma unroll
            for (int mi = 0; mi < 4; ++mi) a[mi] = As[kk][ty * 4 + mi];
            #pragma unroll
            for (int ni = 0; ni < 4; ++ni) b[ni] = Bs[kk][tx * 4 + ni];
            #pragma unroll
            for (int mi = 0; mi < 4; ++mi)
                #pragma unroll
                for (int ni = 0; ni < 4; ++ni)
                    acc[mi][ni] = fmaf(a[mi], b[ni], acc[mi][ni]);
        }
        __syncthreads();
    }

    #pragma unroll
    for (int mi = 0; mi < 4; ++mi) {
        int r = row0 + ty * 4 + mi;
        #pragma unroll
        for (int ni = 0; ni < 4; ++ni) {
            int c = col0 + tx * 4 + ni;
            float v = acc[mi][ni];
            if (bias) v += bias[c];
            C[(size_t)r * ldc + c] = v;
        }
    }
}

// ---------------------------------------------------------------------------
// RoPE in-place on q_rope (all 32 heads) and k_rope (tail of ckv).
// ---------------------------------------------------------------------------
__global__ __launch_bounds__(256)
void rope_kernel(float* __restrict__ q, float* __restrict__ ckv,
                 const float* __restrict__ cosb, const float* __restrict__ sinb)
{
    const int s = blockIdx.x;
    const float* c  = cosb + (size_t)s * ROPE_D;
    const float* si = sinb + (size_t)s * ROPE_D;
    for (int idx = threadIdx.x; idx < (NH + 1) * 32; idx += 256) {
        int hh = idx >> 5;
        int d  = idx & 31;
        float* base = (hh < NH) ? (q + (size_t)s * NQK + hh * QKD + NOPE)
                                : (ckv + (size_t)s * CKV_N + KV_RANK);
        float x0 = base[d];
        float x1 = base[d + 32];
        base[d]      = x0 * c[d]      - x1 * si[d];
        base[d + 32] = x1 * c[d + 32] + x0 * si[d + 32];
    }
}

// ---------------------------------------------------------------------------
// Flash-style sliding-window attention with sink.
// Block = (q-tile of TQ=32, head). 256 threads.
// K-chunks of KC=32 keys staged coalesced into LDS (fp32).
// Scores: 2x2 micro-tile per thread, stride-16 spacing (<=2-way LDS aliasing).
// Online softmax; sink folded in as initial state m=sink, l=1.
// PV: row-group layout, thread (r = t>>3, g = t&7) owns row r, v-dims g*16..+16.
// LDS: 32*196*4 *2 + 32*33*4 = 54.4 KB -> 2 blocks/CU.
// ---------------------------------------------------------------------------
#define TQ 32
#define KC 32
#define QPAD 196   // 192 + 4: de-conflicts row-stride (4 mod 32)
#define SPAD 33

__global__ __launch_bounds__(256)
void attn_tile_kernel(const float* __restrict__ q, const float* __restrict__ kv,
                      const float* __restrict__ ckv, const float* __restrict__ sinks,
                      float* __restrict__ out)
{
    __shared__ float lds_q[TQ * QPAD];
    __shared__ float lds_k[KC * QPAD];
    __shared__ float lds_s[TQ * SPAD];

    const int h  = blockIdx.y;
    const int q0 = blockIdx.x * TQ;
    const int t  = threadIdx.x;

    // stage Q tile (coalesced runs of 192 floats per row)
    for (int e = t; e < TQ * QKD; e += 256) {
        int r = e / QKD, c = e % QKD;
        lds_q[r * QPAD + c] = q[(size_t)(q0 + r) * NQK + h * QKD + c];
    }

    // softmax / PV layout
    const int r = t >> 3;          // query row 0..31
    const int g = t & 7;           // v-dim slice (g*16 .. g*16+15), score cols g*4..g*4+3
    float m_run = sinks[h];
    float l_run = 1.0f;
    float acc[16];
    #pragma unroll
    for (int d = 0; d < 16; ++d) acc[d] = 0.f;

    // score layout
    const int tx = t & 15;         // cols {tx, tx+16}
    const int ty = t >> 4;         // rows {ty, ty+16}

    int cs = q0 - SW + 1;
    if (cs < 0) cs = 0;
    cs &= ~(KC - 1);               // chunk starts are >= 0 always

    for (int c0 = cs; c0 <= q0; c0 += KC) {
        __syncthreads();           // previous chunk fully consumed lds_k / lds_s

        // ---- stage K chunk (coalesced): 32 keys x 192 dims
        for (int e = t; e < KC * QKD; e += 256) {
            int jj = e / QKD, d = e % QKD;
            int j = c0 + jj;       // always in [0, S)
            lds_k[jj * QPAD + d] =
                (d < NOPE) ? kv[(size_t)j * KVN + h * (NOPE + VD) + d]
                           : ckv[(size_t)j * CKV_N + KV_RANK + (d - NOPE)];
        }
        __syncthreads();

        // ---- scores: 2x2 micro-tile, float4 LDS reads
        float s00 = 0.f, s01 = 0.f, s10 = 0.f, s11 = 0.f;
        const float* qa = lds_q + ty * QPAD;
        const float* qb = lds_q + (ty + 16) * QPAD;
        const float* ka = lds_k + tx * QPAD;
        const float* kb = lds_k + (tx + 16) * QPAD;
        #pragma unroll
        for (int d = 0; d < QKD; d += 4) {
            float4 a0 = *(const float4*)(qa + d);
            float4 a1 = *(const float4*)(qb + d);
            float4 b0 = *(const float4*)(ka + d);
            float4 b1 = *(const float4*)(kb + d);
            s00 = fmaf(a0.x, b0.x, s00); s00 = fmaf(a0.y, b0.y, s00);
            s00 = fmaf(a0.z, b0.z, s00); s00 = fmaf(a0.w, b0.w, s00);
            s01 = fmaf(a0.x, b1.x, s01); s01 = fmaf(a0.y, b1.y, s01);
            s01 = fmaf(a0.z, b1.z, s01); s01 = fmaf(a0.w, b1.w, s01);
            s10 = fmaf(a1.x, b0.x, s10); s10 = fmaf(a1.y, b0.y, s10);
            s10 = fmaf(a1.z, b0.z, s10); s10 = fmaf(a1.w, b0.w, s10);
            s11 = fmaf(a1.x, b1.x, s11); s11 = fmaf(a1.y, b1.y, s11);
            s11 = fmaf(a1.z, b1.z, s11); s11 = fmaf(a1.w, b1.w, s11);
        }
        // mask + scale + write to LDS
        {
            int i0 = q0 + ty, i1 = q0 + ty + 16;
            int j0c = c0 + tx, j1c = c0 + tx + 16;
            bool v00 = (j0c <= i0) && (i0 - j0c < SW);
            bool v01 = (j1c <= i0) && (i0 - j1c < SW);
            bool v10 = (j0c <= i1) && (i1 - j0c < SW);
            bool v11 = (j1c <= i1) && (i1 - j1c < SW);
            lds_s[ty * SPAD + tx]               = v00 ? s00 * ATT_SCALE : NEG_INF;
            lds_s[ty * SPAD + tx + 16]          = v01 ? s01 * ATT_SCALE : NEG_INF;
            lds_s[(ty + 16) * SPAD + tx]        = v10 ? s10 * ATT_SCALE : NEG_INF;
            lds_s[(ty + 16) * SPAD + tx + 16]   = v11 ? s11 * ATT_SCALE : NEG_INF;
        }
        __syncthreads();

        // ---- online softmax update (8 lanes per row, contiguous in wave)
        float sv[4];
        float smax = NEG_INF;
        #pragma unroll
        for (int k = 0; k < 4; ++k) {
            sv[k] = lds_s[r * SPAD + g * 4 + k];
            smax = fmaxf(smax, sv[k]);
        }
        #pragma unroll
        for (int off = 1; off < 8; off <<= 1)
            smax = fmaxf(smax, __shfl_xor(smax, off));
        float m_new = fmaxf(m_run, smax);
        float alpha = __expf(m_run - m_new);
        float lsum = 0.f;
        #pragma unroll
        for (int k = 0; k < 4; ++k) {
            float p = __expf(sv[k] - m_new);
            lsum += p;
            lds_s[r * SPAD + g * 4 + k] = p;
        }
        #pragma unroll
        for (int off = 1; off < 8; off <<= 1)
            lsum += __shfl_xor(lsum, off);
        l_run = l_run * alpha + lsum;
        m_run = m_new;
        #pragma unroll
        for (int d = 0; d < 16; ++d) acc[d] *= alpha;
        __syncthreads();

        // ---- PV: acc[d] += p_j * V[j][d]
        const float* vbase = kv + (size_t)c0 * KVN + h * (NOPE + VD) + NOPE + g * 16;
        #pragma unroll 4
        for (int jj = 0; jj < KC; ++jj) {
            float pj = lds_s[r * SPAD + jj];
            const float* v = vbase + (size_t)jj * KVN;
            float4 v0 = *(const float4*)(v);
            float4 v1 = *(const float4*)(v + 4);
            float4 v2 = *(const float4*)(v + 8);
            float4 v3 = *(const float4*)(v + 12);
            acc[0]  = fmaf(pj, v0.x, acc[0]);  acc[1]  = fmaf(pj, v0.y, acc[1]);
            acc[2]  = fmaf(pj, v0.z, acc[2]);  acc[3]  = fmaf(pj, v0.w, acc[3]);
            acc[4]  = fmaf(pj, v1.x, acc[4]);  acc[5]  = fmaf(pj, v1.y, acc[5]);
            acc[6]  = fmaf(pj, v1.z, acc[6]);  acc[7]  = fmaf(pj, v1.w, acc[7]);
            acc[8]  = fmaf(pj, v2.x, acc[8]);  acc[9]  = fmaf(pj, v2.y, acc[9]);
            acc[10] = fmaf(pj, v2.z, acc[10]); acc[11] = fmaf(pj, v2.w, acc[11]);
            acc[12] = fmaf(pj, v3.x, acc[12]); acc[13] = fmaf(pj, v3.y, acc[13]);
            acc[14] = fmaf(pj, v3.z, acc[14]); acc[15] = fmaf(pj, v3.w, acc[15]);
        }
    }

    // ---- epilogue: normalize and store
    float inv_l = 1.0f / l_run;
    float* o = out + (size_t)(q0 + r) * (NH * VD) + h * VD + g * 16;
    float4 o0 = make_float4(acc[0] * inv_l, acc[1] * inv_l, acc[2] * inv_l, acc[3] * inv_l);
    float4 o1 = make_float4(acc[4] * inv_l, acc[5] * inv_l, acc[6] * inv_l, acc[7] * inv_l);
    float4 o2 = make_float4(acc[8] * inv_l, acc[9] * inv_l, acc[10] * inv_l, acc[11] * inv_l);
    float4 o3 = make_float4(acc[12] * inv_l, acc[13] * inv_l, acc[14] * inv_l, acc[15] * inv_l);
    *(float4*)(o)      = o0;
    *(float4*)(o + 4)  = o1;
    *(float4*)(o + 8)  = o2;
    *(float4*)(o + 12) = o3;
}

// ---------------------------------------------------------------------------
extern "C" void kernel_launch(void* const* d_in, const int* in_sizes, int n_in,
                              void* d_out, int out_size, void* d_ws, size_t ws_size,
                              hipStream_t stream) {
    const float* hidden = (const float*)d_in[0];
    const float* cosb   = (const float*)d_in[1];
    const float* sinb   = (const float*)d_in[2];
    const float* Wq     = (const float*)d_in[3];
    const float* bq     = (const float*)d_in[4];
    const float* Wkva   = (const float*)d_in[5];
    const float* bkva   = (const float*)d_in[6];
    const float* Wkvb   = (const float*)d_in[7];
    const float* Wo     = (const float*)d_in[8];
    const float* bo     = (const float*)d_in[9];
    const float* sinks  = (const float*)d_in[10];
    float* out = (float*)d_out;

    float* q        = (float*)d_ws;                 // [S][NH*QKD]
    float* ckv      = q   + (size_t)S_LEN * NQK;    // [S][576]
    float* kv       = ckv + (size_t)S_LEN * CKV_N;  // [S][NH*256]
    float* attn_out = kv  + (size_t)S_LEN * KVN;    // [S][NH*VD]

    const dim3 blk(256);

    gemm_f32<<<dim3(NQK / TN, S_LEN / TM), blk, 0, stream>>>(
        hidden, HID_DIM, Wq, NQK, bq, q, NQK, HID_DIM);

    gemm_f32<<<dim3(CKV_N / TN, S_LEN / TM), blk, 0, stream>>>(
        hidden, HID_DIM, Wkva, CKV_N, bkva, ckv, CKV_N, HID_DIM);

    rope_kernel<<<S_LEN, 256, 0, stream>>>(q, ckv, cosb, sinb);

    gemm_f32<<<dim3(KVN / TN, S_LEN / TM), blk, 0, stream>>>(
        ckv, CKV_N, Wkvb, KVN, nullptr, kv, KVN, KV_RANK);

    attn_tile_kernel<<<dim3(S_LEN / TQ, NH), 256, 0, stream>>>(
        q, kv, ckv, sinks, attn_out);

    gemm_f32<<<dim3(OUT_HID / TN, S_LEN / TM), blk, 0, stream>>>(
        attn_out, NH * VD, Wo, OUT_HID, bo, out, OUT_HID, NH * VD);
}

// Round 3
// 735.600 us; speedup vs baseline: 4.0420x; 3.1723x over previous
//
#include <hip/hip_runtime.h>
#include <hip/hip_bf16.h>
#include <math.h>

#define S_LEN 2048
#define HID_DIM 2048
#define NH 32
#define NOPE 128
#define ROPE_D 64
#define QKD 192           // NOPE + ROPE
#define VD 128
#define KV_RANK 512
#define SW 128
#define NQK (NH*QKD)      // 6144
#define CKV_N (KV_RANK+ROPE_D) // 576
#define KVN (NH*(NOPE+VD))     // 8192
#define OUT_HID 2048
#define ATT_SCALE 0.07216878364870323f  // 192^-0.5
#define NEG_INF (-1e30f)

typedef __bf16 bf16x8 __attribute__((ext_vector_type(8)));
typedef float  f32x4  __attribute__((ext_vector_type(4)));

// ---------------------------------------------------------------------------
// async global->LDS, 16B per lane. LDS dest = wave-uniform base + lane*16.
// ---------------------------------------------------------------------------
__device__ __forceinline__ void async_load16(const void* gp, void* lp) {
    __builtin_amdgcn_global_load_lds(
        (const __attribute__((address_space(1))) void*)gp,
        (__attribute__((address_space(3))) void*)lp, 16, 0, 0);
}

__device__ __forceinline__ void store_out(float* p, float v) { *p = v; }
__device__ __forceinline__ void store_out(__hip_bfloat16* p, float v) { *p = __float2bfloat16(v); }

// ---------------------------------------------------------------------------
// bf16 MFMA GEMM (m97 structure): C[M,N] = A[M,K]bf16 @ Bt[N,K]bf16^T + bias.
// 128x128 tile, BK=32, 256 thr = 4 waves, wave = 64x64 quadrant = 4x4 MFMAs
// of 16x16x32. global_load_lds width=16 staging, single LDS buffer, 2 barriers.
// Fragment layouts (verified m89/m91): A[m=lane&15][k=quad*8+j]; B symmetric
// from Bt rows; C/D col=lane&15, row=quad*4+reg.
// ---------------------------------------------------------------------------
template<typename OutT>
__global__ __launch_bounds__(256)
void gemm_bf16(const __hip_bfloat16* __restrict__ A, int lda,
               const __hip_bfloat16* __restrict__ Bt, int ldbt,
               const float* __restrict__ bias,
               OutT* __restrict__ C, int ldc, int K, int nreal)
{
    __shared__ __hip_bfloat16 As[128 * 32];
    __shared__ __hip_bfloat16 Bs[128 * 32];

    const int t = threadIdx.x;
    const int w = t >> 6;
    const int L = t & 63;
    const int lane15 = L & 15, quad = L >> 4;
    const int wm = (w & 1) * 64, wn = (w >> 1) * 64;
    const int m0 = blockIdx.y * 128;
    const int n0 = blockIdx.x * 128;

    f32x4 acc[4][4];
    #pragma unroll
    for (int mi = 0; mi < 4; ++mi)
        #pragma unroll
        for (int ni = 0; ni < 4; ++ni)
            acc[mi][ni] = (f32x4){0.f, 0.f, 0.f, 0.f};

    for (int k0 = 0; k0 < K; k0 += 32) {
        __syncthreads();   // previous chunk's frags consumed
        #pragma unroll
        for (int i = 0; i < 2; ++i) {
            const int slot = w * 64 + i * 256 + L;      // per-lane
            const int base = (w * 64 + i * 256) * 8;    // wave-uniform elems
            async_load16(A  + (size_t)(m0 + (slot >> 2)) * lda  + k0 + (slot & 3) * 8,
                         (void*)(As + base));
            async_load16(Bt + (size_t)(n0 + (slot >> 2)) * ldbt + k0 + (slot & 3) * 8,
                         (void*)(Bs + base));
        }
        __syncthreads();   // compiler drains vmcnt before barrier

        bf16x8 af[4], bfr[4];
        #pragma unroll
        for (int mi = 0; mi < 4; ++mi)
            af[mi] = *(const bf16x8*)(const void*)(As + (wm + mi * 16 + lane15) * 32 + quad * 8);
        #pragma unroll
        for (int ni = 0; ni < 4; ++ni)
            bfr[ni] = *(const bf16x8*)(const void*)(Bs + (wn + ni * 16 + lane15) * 32 + quad * 8);
        #pragma unroll
        for (int mi = 0; mi < 4; ++mi)
            #pragma unroll
            for (int ni = 0; ni < 4; ++ni)
                acc[mi][ni] = __builtin_amdgcn_mfma_f32_16x16x32_bf16(af[mi], bfr[ni], acc[mi][ni], 0, 0, 0);
    }

    #pragma unroll
    for (int mi = 0; mi < 4; ++mi) {
        const int rbase = m0 + wm + mi * 16 + quad * 4;
        #pragma unroll
        for (int ni = 0; ni < 4; ++ni) {
            const int c = n0 + wn + ni * 16 + lane15;
            if (c < nreal) {
                const float bv = bias ? bias[c] : 0.f;
                #pragma unroll
                for (int p = 0; p < 4; ++p)
                    store_out(C + (size_t)(rbase + p) * ldc + c, acc[mi][ni][p] + bv);
            }
        }
    }
}

// ---------------------------------------------------------------------------
// fp32 -> bf16 transpose-convert: dst[c][r] = bf16(src[r][c]). 32x32 LDS tile.
// rows, cols both multiples of 32.
// ---------------------------------------------------------------------------
__global__ __launch_bounds__(256)
void transpose_cvt(const float* __restrict__ src, __hip_bfloat16* __restrict__ dst,
                   int rows, int cols)
{
    __shared__ float tile[32][33];
    const int tx = threadIdx.x & 31;
    const int ty = threadIdx.x >> 5;   // 0..7
    const int r0 = blockIdx.y * 32;
    const int c0 = blockIdx.x * 32;
    #pragma unroll
    for (int i = 0; i < 4; ++i)
        tile[ty + i * 8][tx] = src[(size_t)(r0 + ty + i * 8) * cols + c0 + tx];
    __syncthreads();
    #pragma unroll
    for (int i = 0; i < 4; ++i)
        dst[(size_t)(c0 + ty + i * 8) * rows + r0 + tx] = __float2bfloat16(tile[tx][ty + i * 8]);
}

// fp32 -> bf16 elementwise (n multiple of 4)
__global__ __launch_bounds__(256)
void cvt_bf16_kernel(const float* __restrict__ src, __hip_bfloat16* __restrict__ dst, int n4)
{
    int i = blockIdx.x * 256 + threadIdx.x;
    if (i < n4) {
        float4 v = ((const float4*)src)[i];
        dst[i * 4 + 0] = __float2bfloat16(v.x);
        dst[i * 4 + 1] = __float2bfloat16(v.y);
        dst[i * 4 + 2] = __float2bfloat16(v.z);
        dst[i * 4 + 3] = __float2bfloat16(v.w);
    }
}

// kv_lat slice of ckv (lda 576, first 512 cols) -> bf16 [2048][512]
__global__ __launch_bounds__(256)
void cvt_kvlat_kernel(const float* __restrict__ ckv, __hip_bfloat16* __restrict__ dst)
{
    int i = blockIdx.x * 256 + threadIdx.x;   // 0 .. 2048*512-1
    int r = i >> 9, c = i & 511;
    dst[i] = __float2bfloat16(ckv[(size_t)r * CKV_N + c]);
}

// ---------------------------------------------------------------------------
// RoPE: q (bf16, per head) and k_rope tail of ckv (fp32), in place.
// ---------------------------------------------------------------------------
__global__ __launch_bounds__(256)
void rope_kernel(__hip_bfloat16* __restrict__ q, float* __restrict__ ckv,
                 const float* __restrict__ cosb, const float* __restrict__ sinb)
{
    const int s = blockIdx.x;
    const float* c  = cosb + (size_t)s * ROPE_D;
    const float* si = sinb + (size_t)s * ROPE_D;
    for (int idx = threadIdx.x; idx < NH * 32; idx += 256) {
        int hh = idx >> 5;
        int d  = idx & 31;
        __hip_bfloat16* base = q + (size_t)s * NQK + hh * QKD + NOPE;
        float x0 = __bfloat162float(base[d]);
        float x1 = __bfloat162float(base[d + 32]);
        base[d]      = __float2bfloat16(x0 * c[d]      - x1 * si[d]);
        base[d + 32] = __float2bfloat16(x1 * c[d + 32] + x0 * si[d + 32]);
    }
    if (threadIdx.x < 32) {
        int d = threadIdx.x;
        float* base = ckv + (size_t)s * CKV_N + KV_RANK;
        float x0 = base[d], x1 = base[d + 32];
        base[d]      = x0 * c[d]      - x1 * si[d];
        base[d + 32] = x1 * c[d + 32] + x0 * si[d + 32];
    }
}

// ---------------------------------------------------------------------------
// Flash-style sliding-window attention with sink. bf16 q/kv inputs, bf16 out.
// Block = (q-tile 32, head), 256 threads. LDS 54.4 KB -> 2 blocks/CU.
// ---------------------------------------------------------------------------
#define TQ 32
#define KC 32
#define QPAD 196
#define SPAD 33

__global__ __launch_bounds__(256)
void attn_tile_kernel(const __hip_bfloat16* __restrict__ q,
                      const __hip_bfloat16* __restrict__ kv,
                      const float* __restrict__ ckv,
                      const float* __restrict__ sinks,
                      __hip_bfloat16* __restrict__ out)
{
    __shared__ float lds_q[TQ * QPAD];
    __shared__ float lds_k[KC * QPAD];
    __shared__ float lds_s[TQ * SPAD];

    const int h  = blockIdx.y;
    const int q0 = blockIdx.x * TQ;
    const int t  = threadIdx.x;

    for (int e = t; e < TQ * QKD; e += 256) {
        int r = e / QKD, cc = e % QKD;
        lds_q[r * QPAD + cc] = __bfloat162float(q[(size_t)(q0 + r) * NQK + h * QKD + cc]);
    }

    const int r = t >> 3;          // query row 0..31
    const int g = t & 7;           // slice
    float m_run = sinks[h];
    float l_run = 1.0f;
    float acc[16];
    #pragma unroll
    for (int d = 0; d < 16; ++d) acc[d] = 0.f;

    const int tx = t & 15;
    const int ty = t >> 4;

    int cs = q0 - SW + 1;
    if (cs < 0) cs = 0;
    cs &= ~(KC - 1);

    for (int c0 = cs; c0 <= q0; c0 += KC) {
        __syncthreads();

        for (int e = t; e < KC * QKD; e += 256) {
            int jj = e / QKD, d = e % QKD;
            int j = c0 + jj;
            lds_k[jj * QPAD + d] =
                (d < NOPE) ? __bfloat162float(kv[(size_t)j * KVN + h * (NOPE + VD) + d])
                           : ckv[(size_t)j * CKV_N + KV_RANK + (d - NOPE)];
        }
        __syncthreads();

        float s00 = 0.f, s01 = 0.f, s10 = 0.f, s11 = 0.f;
        const float* qa = lds_q + ty * QPAD;
        const float* qb = lds_q + (ty + 16) * QPAD;
        const float* ka = lds_k + tx * QPAD;
        const float* kb = lds_k + (tx + 16) * QPAD;
        #pragma unroll
        for (int d = 0; d < QKD; d += 4) {
            float4 a0 = *(const float4*)(qa + d);
            float4 a1 = *(const float4*)(qb + d);
            float4 b0 = *(const float4*)(ka + d);
            float4 b1 = *(const float4*)(kb + d);
            s00 = fmaf(a0.x, b0.x, s00); s00 = fmaf(a0.y, b0.y, s00);
            s00 = fmaf(a0.z, b0.z, s00); s00 = fmaf(a0.w, b0.w, s00);
            s01 = fmaf(a0.x, b1.x, s01); s01 = fmaf(a0.y, b1.y, s01);
            s01 = fmaf(a0.z, b1.z, s01); s01 = fmaf(a0.w, b1.w, s01);
            s10 = fmaf(a1.x, b0.x, s10); s10 = fmaf(a1.y, b0.y, s10);
            s10 = fmaf(a1.z, b0.z, s10); s10 = fmaf(a1.w, b0.w, s10);
            s11 = fmaf(a1.x, b1.x, s11); s11 = fmaf(a1.y, b1.y, s11);
            s11 = fmaf(a1.z, b1.z, s11); s11 = fmaf(a1.w, b1.w, s11);
        }
        {
            int i0 = q0 + ty, i1 = q0 + ty + 16;
            int j0c = c0 + tx, j1c = c0 + tx + 16;
            bool v00 = (j0c <= i0) && (i0 - j0c < SW);
            bool v01 = (j1c <= i0) && (i0 - j1c < SW);
            bool v10 = (j0c <= i1) && (i1 - j0c < SW);
            bool v11 = (j1c <= i1) && (i1 - j1c < SW);
            lds_s[ty * SPAD + tx]             = v00 ? s00 * ATT_SCALE : NEG_INF;
            lds_s[ty * SPAD + tx + 16]        = v01 ? s01 * ATT_SCALE : NEG_INF;
            lds_s[(ty + 16) * SPAD + tx]      = v10 ? s10 * ATT_SCALE : NEG_INF;
            lds_s[(ty + 16) * SPAD + tx + 16] = v11 ? s11 * ATT_SCALE : NEG_INF;
        }
        __syncthreads();

        float sv[4];
        float smax = NEG_INF;
        #pragma unroll
        for (int k = 0; k < 4; ++k) {
            sv[k] = lds_s[r * SPAD + g * 4 + k];
            smax = fmaxf(smax, sv[k]);
        }
        #pragma unroll
        for (int off = 1; off < 8; off <<= 1)
            smax = fmaxf(smax, __shfl_xor(smax, off));
        float m_new = fmaxf(m_run, smax);
        float alpha = __expf(m_run - m_new);
        float lsum = 0.f;
        #pragma unroll
        for (int k = 0; k < 4; ++k) {
            float p = __expf(sv[k] - m_new);
            lsum += p;
            lds_s[r * SPAD + g * 4 + k] = p;
        }
        #pragma unroll
        for (int off = 1; off < 8; off <<= 1)
            lsum += __shfl_xor(lsum, off);
        l_run = l_run * alpha + lsum;
        m_run = m_new;
        #pragma unroll
        for (int d = 0; d < 16; ++d) acc[d] *= alpha;
        __syncthreads();

        // PV: V read directly as bf16 (16 elems = 2x16B per thread)
        const __hip_bfloat16* vbase = kv + (size_t)c0 * KVN + h * (NOPE + VD) + NOPE + g * 16;
        #pragma unroll 4
        for (int jj = 0; jj < KC; ++jj) {
            float pj = lds_s[r * SPAD + jj];
            const __hip_bfloat16* vr = vbase + (size_t)jj * KVN;
            bf16x8 v0 = *(const bf16x8*)(const void*)(vr);
            bf16x8 v1 = *(const bf16x8*)(const void*)(vr + 8);
            #pragma unroll
            for (int d = 0; d < 8; ++d) acc[d]     = fmaf(pj, (float)v0[d], acc[d]);
            #pragma unroll
            for (int d = 0; d < 8; ++d) acc[d + 8] = fmaf(pj, (float)v1[d], acc[d + 8]);
        }
    }

    float inv_l = 1.0f / l_run;
    __hip_bfloat16* o = out + (size_t)(q0 + r) * (NH * VD) + h * VD + g * 16;
    #pragma unroll
    for (int d = 0; d < 16; ++d)
        o[d] = __float2bfloat16(acc[d] * inv_l);
}

// ---------------------------------------------------------------------------
extern "C" void kernel_launch(void* const* d_in, const int* in_sizes, int n_in,
                              void* d_out, int out_size, void* d_ws, size_t ws_size,
                              hipStream_t stream) {
    const float* hidden = (const float*)d_in[0];
    const float* cosb   = (const float*)d_in[1];
    const float* sinb   = (const float*)d_in[2];
    const float* Wq     = (const float*)d_in[3];
    const float* bq     = (const float*)d_in[4];
    const float* Wkva   = (const float*)d_in[5];
    const float* bkva   = (const float*)d_in[6];
    const float* Wkvb   = (const float*)d_in[7];
    const float* Wo     = (const float*)d_in[8];
    const float* bo     = (const float*)d_in[9];
    const float* sinks  = (const float*)d_in[10];
    float* out = (float*)d_out;

    // workspace carve-up (~143.7 MB)
    uint8_t* p = (uint8_t*)d_ws;
    __hip_bfloat16* q_bf    = (__hip_bfloat16*)p; p += (size_t)S_LEN * NQK * 2;       // 25.2 MB
    float*          ckv     = (float*)p;          p += (size_t)S_LEN * CKV_N * 4;     //  4.7 MB
    __hip_bfloat16* kv_bf   = (__hip_bfloat16*)p; p += (size_t)S_LEN * KVN * 2;       // 33.6 MB
    __hip_bfloat16* attn_bf = (__hip_bfloat16*)p; p += (size_t)S_LEN * NH * VD * 2;   // 16.8 MB
    __hip_bfloat16* hid_bf  = (__hip_bfloat16*)p; p += (size_t)S_LEN * HID_DIM * 2;   //  8.4 MB
    __hip_bfloat16* WqT     = (__hip_bfloat16*)p; p += (size_t)NQK * HID_DIM * 2;     // 25.2 MB
    __hip_bfloat16* WkvaT   = (__hip_bfloat16*)p; p += (size_t)640 * HID_DIM * 2;     //  2.6 MB (576 padded to 640)
    __hip_bfloat16* WkvbT   = (__hip_bfloat16*)p; p += (size_t)KVN * KV_RANK * 2;     //  8.4 MB
    __hip_bfloat16* WoT     = (__hip_bfloat16*)p; p += (size_t)OUT_HID * (NH*VD) * 2; // 16.8 MB
    __hip_bfloat16* kvlat   = (__hip_bfloat16*)p; p += (size_t)S_LEN * KV_RANK * 2;   //  2.1 MB

    // --- weight / activation conversions (independent) ---
    cvt_bf16_kernel<<<(S_LEN * HID_DIM / 4 + 255) / 256, 256, 0, stream>>>(
        hidden, hid_bf, S_LEN * HID_DIM / 4);
    transpose_cvt<<<dim3(NQK / 32, HID_DIM / 32), 256, 0, stream>>>(Wq, WqT, HID_DIM, NQK);
    transpose_cvt<<<dim3(CKV_N / 32, HID_DIM / 32), 256, 0, stream>>>(Wkva, WkvaT, HID_DIM, CKV_N);
    transpose_cvt<<<dim3(KVN / 32, KV_RANK / 32), 256, 0, stream>>>(Wkvb, WkvbT, KV_RANK, KVN);
    transpose_cvt<<<dim3(OUT_HID / 32, (NH * VD) / 32), 256, 0, stream>>>(Wo, WoT, NH * VD, OUT_HID);

    // --- q = hidden @ Wq + bq  (bf16 out) ---
    gemm_bf16<__hip_bfloat16><<<dim3(NQK / 128, S_LEN / 128), 256, 0, stream>>>(
        hid_bf, HID_DIM, WqT, HID_DIM, bq, q_bf, NQK, HID_DIM, NQK);

    // --- ckv = hidden @ Wkva + bkva  (fp32 out, N=576 masked via 5 tiles) ---
    gemm_bf16<float><<<dim3(5, S_LEN / 128), 256, 0, stream>>>(
        hid_bf, HID_DIM, WkvaT, HID_DIM, bkva, ckv, CKV_N, HID_DIM, CKV_N);

    // --- RoPE ---
    rope_kernel<<<S_LEN, 256, 0, stream>>>(q_bf, ckv, cosb, sinb);

    // --- kv_lat -> bf16 ---
    cvt_kvlat_kernel<<<(S_LEN * KV_RANK) / 256, 256, 0, stream>>>(ckv, kvlat);

    // --- kv = kv_lat @ Wkvb  (bf16 out) ---
    gemm_bf16<__hip_bfloat16><<<dim3(KVN / 128, S_LEN / 128), 256, 0, stream>>>(
        kvlat, KV_RANK, WkvbT, KV_RANK, nullptr, kv_bf, KVN, KV_RANK, KVN);

    // --- attention ---
    attn_tile_kernel<<<dim3(S_LEN / TQ, NH), 256, 0, stream>>>(
        q_bf, kv_bf, ckv, sinks, attn_bf);

    // --- out = attn @ Wo + bo  (fp32 out) ---
    gemm_bf16<float><<<dim3(OUT_HID / 128, S_LEN / 128), 256, 0, stream>>>(
        attn_bf, NH * VD, WoT, NH * VD, bo, out, OUT_HID, NH * VD, OUT_HID);
}

// Round 4
// 477.642 us; speedup vs baseline: 6.2249x; 1.5401x over previous
//
#include <hip/hip_runtime.h>
#include <hip/hip_bf16.h>
#include <math.h>

#define S_LEN 2048
#define HID_DIM 2048
#define NH 32
#define NOPE 128
#define ROPE_D 64
#define QKD 192           // NOPE + ROPE
#define VD 128
#define KV_RANK 512
#define SW 128
#define NQK (NH*QKD)      // 6144
#define CKV_N (KV_RANK+ROPE_D) // 576
#define KVN (NH*(NOPE+VD))     // 8192
#define KNW (NH*NOPE)          // 4096
#define OUT_HID 2048
#define ATT_SCALE 0.07216878364870323f  // 192^-0.5
#define NEG_INF (-1e30f)

typedef __bf16 bf16x8 __attribute__((ext_vector_type(8)));
typedef float  f32x4  __attribute__((ext_vector_type(4)));

// ---------------------------------------------------------------------------
// async global->LDS, 16B per lane. LDS dest = wave-uniform base + lane*16.
// ---------------------------------------------------------------------------
__device__ __forceinline__ void async_load16(const void* gp, void* lp) {
    __builtin_amdgcn_global_load_lds(
        (const __attribute__((address_space(1))) void*)gp,
        (__attribute__((address_space(3))) void*)lp, 16, 0, 0);
}

__device__ __forceinline__ void store_out(float* p, float v) { *p = v; }
__device__ __forceinline__ void store_out(__hip_bfloat16* p, float v) { *p = __float2bfloat16(v); }

// ---------------------------------------------------------------------------
// bf16 MFMA GEMM (m97 structure): C[M,N] = A[M,K]bf16 @ Bt[N,K]bf16^T + bias.
// 128x128 tile, BK=32, 4 waves, wave = 64x64 quadrant of 4x4 16x16x32 MFMAs.
// ---------------------------------------------------------------------------
template<typename OutT>
__global__ __launch_bounds__(256)
void gemm_bf16(const __hip_bfloat16* __restrict__ A, int lda,
               const __hip_bfloat16* __restrict__ Bt, int ldbt,
               const float* __restrict__ bias,
               OutT* __restrict__ C, int ldc, int K, int nreal)
{
    __shared__ __hip_bfloat16 As[128 * 32];
    __shared__ __hip_bfloat16 Bs[128 * 32];

    const int t = threadIdx.x;
    const int w = t >> 6;
    const int L = t & 63;
    const int lane15 = L & 15, quad = L >> 4;
    const int wm = (w & 1) * 64, wn = (w >> 1) * 64;
    const int m0 = blockIdx.y * 128;
    const int n0 = blockIdx.x * 128;

    f32x4 acc[4][4];
    #pragma unroll
    for (int mi = 0; mi < 4; ++mi)
        #pragma unroll
        for (int ni = 0; ni < 4; ++ni)
            acc[mi][ni] = (f32x4){0.f, 0.f, 0.f, 0.f};

    for (int k0 = 0; k0 < K; k0 += 32) {
        __syncthreads();
        #pragma unroll
        for (int i = 0; i < 2; ++i) {
            const int slot = w * 64 + i * 256 + L;
            const int base = (w * 64 + i * 256) * 8;
            async_load16(A  + (size_t)(m0 + (slot >> 2)) * lda  + k0 + (slot & 3) * 8,
                         (void*)(As + base));
            async_load16(Bt + (size_t)(n0 + (slot >> 2)) * ldbt + k0 + (slot & 3) * 8,
                         (void*)(Bs + base));
        }
        __syncthreads();

        bf16x8 af[4], bfr[4];
        #pragma unroll
        for (int mi = 0; mi < 4; ++mi)
            af[mi] = *(const bf16x8*)(const void*)(As + (wm + mi * 16 + lane15) * 32 + quad * 8);
        #pragma unroll
        for (int ni = 0; ni < 4; ++ni)
            bfr[ni] = *(const bf16x8*)(const void*)(Bs + (wn + ni * 16 + lane15) * 32 + quad * 8);
        #pragma unroll
        for (int mi = 0; mi < 4; ++mi)
            #pragma unroll
            for (int ni = 0; ni < 4; ++ni)
                acc[mi][ni] = __builtin_amdgcn_mfma_f32_16x16x32_bf16(af[mi], bfr[ni], acc[mi][ni], 0, 0, 0);
    }

    #pragma unroll
    for (int mi = 0; mi < 4; ++mi) {
        const int rbase = m0 + wm + mi * 16 + quad * 4;
        #pragma unroll
        for (int ni = 0; ni < 4; ++ni) {
            const int c = n0 + wn + ni * 16 + lane15;
            if (c < nreal) {
                const float bv = bias ? bias[c] : 0.f;
                #pragma unroll
                for (int p = 0; p < 4; ++p)
                    store_out(C + (size_t)(rbase + p) * ldc + c, acc[mi][ni][p] + bv);
            }
        }
    }
}

// ---------------------------------------------------------------------------
// kv up-proj GEMM with split epilogue: C = kvlat[2048x512] @ WkvbT^T [8192x512].
// Column c: h = c>>8, d = c&255. d<128 -> kn[s][h*128+d]; d>=128 -> transposed
// store vt[(h*128+(d-128))][s] (4 contiguous rows per lane = one ushort4).
// ---------------------------------------------------------------------------
__global__ __launch_bounds__(256)
void gemm_kv(const __hip_bfloat16* __restrict__ A,
             const __hip_bfloat16* __restrict__ Bt,
             __hip_bfloat16* __restrict__ kn,
             __hip_bfloat16* __restrict__ vt)
{
    __shared__ __hip_bfloat16 As[128 * 32];
    __shared__ __hip_bfloat16 Bs[128 * 32];

    const int t = threadIdx.x;
    const int w = t >> 6;
    const int L = t & 63;
    const int lane15 = L & 15, quad = L >> 4;
    const int wm = (w & 1) * 64, wn = (w >> 1) * 64;
    const int m0 = blockIdx.y * 128;
    const int n0 = blockIdx.x * 128;

    f32x4 acc[4][4];
    #pragma unroll
    for (int mi = 0; mi < 4; ++mi)
        #pragma unroll
        for (int ni = 0; ni < 4; ++ni)
            acc[mi][ni] = (f32x4){0.f, 0.f, 0.f, 0.f};

    for (int k0 = 0; k0 < KV_RANK; k0 += 32) {
        __syncthreads();
        #pragma unroll
        for (int i = 0; i < 2; ++i) {
            const int slot = w * 64 + i * 256 + L;
            const int base = (w * 64 + i * 256) * 8;
            async_load16(A  + (size_t)(m0 + (slot >> 2)) * KV_RANK + k0 + (slot & 3) * 8,
                         (void*)(As + base));
            async_load16(Bt + (size_t)(n0 + (slot >> 2)) * KV_RANK + k0 + (slot & 3) * 8,
                         (void*)(Bs + base));
        }
        __syncthreads();

        bf16x8 af[4], bfr[4];
        #pragma unroll
        for (int mi = 0; mi < 4; ++mi)
            af[mi] = *(const bf16x8*)(const void*)(As + (wm + mi * 16 + lane15) * 32 + quad * 8);
        #pragma unroll
        for (int ni = 0; ni < 4; ++ni)
            bfr[ni] = *(const bf16x8*)(const void*)(Bs + (wn + ni * 16 + lane15) * 32 + quad * 8);
        #pragma unroll
        for (int mi = 0; mi < 4; ++mi)
            #pragma unroll
            for (int ni = 0; ni < 4; ++ni)
                acc[mi][ni] = __builtin_amdgcn_mfma_f32_16x16x32_bf16(af[mi], bfr[ni], acc[mi][ni], 0, 0, 0);
    }

    #pragma unroll
    for (int mi = 0; mi < 4; ++mi) {
        const int rbase = m0 + wm + mi * 16 + quad * 4;   // s, 4 consecutive
        #pragma unroll
        for (int ni = 0; ni < 4; ++ni) {
            const int c = n0 + wn + ni * 16 + lane15;
            const int h = c >> 8, d = c & 255;
            if (d < NOPE) {
                #pragma unroll
                for (int p = 0; p < 4; ++p)
                    kn[(size_t)(rbase + p) * KNW + h * NOPE + d] = __float2bfloat16(acc[mi][ni][p]);
            } else {
                ushort4 pk;
                __hip_bfloat16 b0 = __float2bfloat16(acc[mi][ni][0]);
                __hip_bfloat16 b1 = __float2bfloat16(acc[mi][ni][1]);
                __hip_bfloat16 b2 = __float2bfloat16(acc[mi][ni][2]);
                __hip_bfloat16 b3 = __float2bfloat16(acc[mi][ni][3]);
                pk.x = *(unsigned short*)&b0; pk.y = *(unsigned short*)&b1;
                pk.z = *(unsigned short*)&b2; pk.w = *(unsigned short*)&b3;
                *(ushort4*)(vt + (size_t)(h * VD + (d - NOPE)) * S_LEN + rbase) = pk;
            }
        }
    }
}

// ---------------------------------------------------------------------------
// fp32 -> bf16 transpose-convert
// ---------------------------------------------------------------------------
__global__ __launch_bounds__(256)
void transpose_cvt(const float* __restrict__ src, __hip_bfloat16* __restrict__ dst,
                   int rows, int cols)
{
    __shared__ float tile[32][33];
    const int tx = threadIdx.x & 31;
    const int ty = threadIdx.x >> 5;
    const int r0 = blockIdx.y * 32;
    const int c0 = blockIdx.x * 32;
    #pragma unroll
    for (int i = 0; i < 4; ++i)
        tile[ty + i * 8][tx] = src[(size_t)(r0 + ty + i * 8) * cols + c0 + tx];
    __syncthreads();
    #pragma unroll
    for (int i = 0; i < 4; ++i)
        dst[(size_t)(c0 + ty + i * 8) * rows + r0 + tx] = __float2bfloat16(tile[tx][ty + i * 8]);
}

__global__ __launch_bounds__(256)
void cvt_bf16_kernel(const float* __restrict__ src, __hip_bfloat16* __restrict__ dst, int n4)
{
    int i = blockIdx.x * 256 + threadIdx.x;
    if (i < n4) {
        float4 v = ((const float4*)src)[i];
        dst[i * 4 + 0] = __float2bfloat16(v.x);
        dst[i * 4 + 1] = __float2bfloat16(v.y);
        dst[i * 4 + 2] = __float2bfloat16(v.z);
        dst[i * 4 + 3] = __float2bfloat16(v.w);
    }
}

__global__ __launch_bounds__(256)
void cvt_kvlat_kernel(const float* __restrict__ ckv, __hip_bfloat16* __restrict__ dst)
{
    int i = blockIdx.x * 256 + threadIdx.x;
    int r = i >> 9, c = i & 511;
    dst[i] = __float2bfloat16(ckv[(size_t)r * CKV_N + c]);
}

// ---------------------------------------------------------------------------
// RoPE: q (bf16, per head) in place; k_rope tail of ckv (fp32) -> kr bf16.
// ---------------------------------------------------------------------------
__global__ __launch_bounds__(256)
void rope_kernel(__hip_bfloat16* __restrict__ q, const float* __restrict__ ckv,
                 __hip_bfloat16* __restrict__ kr,
                 const float* __restrict__ cosb, const float* __restrict__ sinb)
{
    const int s = blockIdx.x;
    const float* c  = cosb + (size_t)s * ROPE_D;
    const float* si = sinb + (size_t)s * ROPE_D;
    for (int idx = threadIdx.x; idx < NH * 32; idx += 256) {
        int hh = idx >> 5;
        int d  = idx & 31;
        __hip_bfloat16* base = q + (size_t)s * NQK + hh * QKD + NOPE;
        float x0 = __bfloat162float(base[d]);
        float x1 = __bfloat162float(base[d + 32]);
        base[d]      = __float2bfloat16(x0 * c[d]      - x1 * si[d]);
        base[d + 32] = __float2bfloat16(x1 * c[d + 32] + x0 * si[d + 32]);
    }
    if (threadIdx.x < 32) {
        int d = threadIdx.x;
        const float* base = ckv + (size_t)s * CKV_N + KV_RANK;
        float x0 = base[d], x1 = base[d + 32];
        kr[(size_t)s * ROPE_D + d]      = __float2bfloat16(x0 * c[d]      - x1 * si[d]);
        kr[(size_t)s * ROPE_D + d + 32] = __float2bfloat16(x1 * c[d + 32] + x0 * si[d + 32]);
    }
}

// ---------------------------------------------------------------------------
// MFMA sliding-window attention with sink. Block = (32-query tile, head),
// 256 thr = 4 waves. Window=128 -> <=5 chunks of 32 keys; compute ALL scores
// (QK^T via MFMA, B-frags straight from global kn/kr), one softmax (sink
// exact), then PV via MFMA (A-frags from LDS P, B-frags from global vt).
// Only 2 barriers per block. LDS = 32*170*4 + 32*168*2 = 32.3 KB.
// QK wave layout: wm=(w&1)*16 queries, wn=(w>>1)*16 keys (16x16 tile each).
// PV wave layout: wm queries, (w>>1)*64 + ni*16 vdims.
// ---------------------------------------------------------------------------
#define SS 170   // lds_s fp32 stride: 4*170 % 32 = 8 -> quads de-conflicted
#define SP 168   // lds_p bf16 stride: 336B row = 2-way alias (free), 16B-aligned

__global__ __launch_bounds__(256)
void attn_mfma_kernel(const __hip_bfloat16* __restrict__ q,
                      const __hip_bfloat16* __restrict__ kn,
                      const __hip_bfloat16* __restrict__ kr,
                      const __hip_bfloat16* __restrict__ vt,
                      const float* __restrict__ sinks,
                      __hip_bfloat16* __restrict__ out)
{
    __shared__ float lds_s[32 * SS];
    __shared__ __hip_bfloat16 lds_p[32 * SP];

    const int h  = blockIdx.y;
    const int q0 = blockIdx.x * 32;
    const int t  = threadIdx.x;
    const int w  = t >> 6;
    const int L  = t & 63;
    const int lane15 = L & 15, quad = L >> 4;
    const int wm = (w & 1) * 16;

    int lo = q0 - SW + 1; if (lo < 0) lo = 0;
    const int cb = lo & ~31;
    const int nc = ((q0 - cb) >> 5) + 1;    // 1..5

    // Q fragments, held in registers for all chunks
    bf16x8 qf[6];
    {
        const __hip_bfloat16* qrow = q + (size_t)(q0 + wm + lane15) * NQK + h * QKD;
        #pragma unroll
        for (int kk = 0; kk < 6; ++kk)
            qf[kk] = *(const bf16x8*)(const void*)(qrow + kk * 32 + quad * 8);
    }

    // ---- QK^T: each wave one 16x16 score quadrant per chunk
    {
        const int wn = (w >> 1) * 16;
        for (int cc = 0; cc < nc; ++cc) {
            const int kbase = cb + cc * 32 + wn;
            const __hip_bfloat16* knrow = kn + (size_t)(kbase + lane15) * KNW + h * NOPE;
            const __hip_bfloat16* krrow = kr + (size_t)(kbase + lane15) * ROPE_D;
            f32x4 s = (f32x4){0.f, 0.f, 0.f, 0.f};
            #pragma unroll
            for (int kk = 0; kk < 4; ++kk) {
                bf16x8 bf = *(const bf16x8*)(const void*)(knrow + kk * 32 + quad * 8);
                s = __builtin_amdgcn_mfma_f32_16x16x32_bf16(qf[kk], bf, s, 0, 0, 0);
            }
            #pragma unroll
            for (int kk = 0; kk < 2; ++kk) {
                bf16x8 bf = *(const bf16x8*)(const void*)(krrow + kk * 32 + quad * 8);
                s = __builtin_amdgcn_mfma_f32_16x16x32_bf16(qf[4 + kk], bf, s, 0, 0, 0);
            }
            const int j = kbase + lane15;
            #pragma unroll
            for (int p = 0; p < 4; ++p) {
                const int i = q0 + wm + quad * 4 + p;
                const bool ok = (j <= i) && (i - j < SW);
                lds_s[(wm + quad * 4 + p) * SS + cc * 32 + wn + lane15] =
                    ok ? s[p] * ATT_SCALE : NEG_INF;
            }
        }
    }
    __syncthreads();

    // ---- softmax per row (8 threads/row), sink exact, 1/l folded into P
    {
        const int r = t >> 3, g = t & 7;
        const int ncols = nc * 32;
        const float sink = sinks[h];
        float mx = sink;
        for (int c = g; c < ncols; c += 8)
            mx = fmaxf(mx, lds_s[r * SS + c]);
        #pragma unroll
        for (int off = 1; off < 8; off <<= 1)
            mx = fmaxf(mx, __shfl_xor(mx, off));
        float sum = 0.f;
        for (int c = g; c < ncols; c += 8) {
            float e = __expf(lds_s[r * SS + c] - mx);
            lds_s[r * SS + c] = e;
            sum += e;
        }
        #pragma unroll
        for (int off = 1; off < 8; off <<= 1)
            sum += __shfl_xor(sum, off);
        const float inv = 1.0f / (sum + __expf(sink - mx));
        for (int c = g; c < ncols; c += 8)
            lds_p[r * SP + c] = __float2bfloat16(lds_s[r * SS + c] * inv);
    }
    __syncthreads();

    // ---- PV: wave w -> queries wm..wm+15, vdims (w>>1)*64 .. +64
    f32x4 oacc[4];
    #pragma unroll
    for (int ni = 0; ni < 4; ++ni) oacc[ni] = (f32x4){0.f, 0.f, 0.f, 0.f};
    const int vrow0 = h * VD + (w >> 1) * 64;
    for (int cc = 0; cc < nc; ++cc) {
        bf16x8 ap = *(const bf16x8*)(const void*)(lds_p + (wm + lane15) * SP + cc * 32 + quad * 8);
        const int koff = cb + cc * 32 + quad * 8;
        #pragma unroll
        for (int ni = 0; ni < 4; ++ni) {
            bf16x8 bv = *(const bf16x8*)(const void*)(vt + (size_t)(vrow0 + ni * 16 + lane15) * S_LEN + koff);
            oacc[ni] = __builtin_amdgcn_mfma_f32_16x16x32_bf16(ap, bv, oacc[ni], 0, 0, 0);
        }
    }

    #pragma unroll
    for (int ni = 0; ni < 4; ++ni) {
        const int col = h * VD + (w >> 1) * 64 + ni * 16 + lane15;
        #pragma unroll
        for (int p = 0; p < 4; ++p) {
            const int row = q0 + wm + quad * 4 + p;
            out[(size_t)row * (NH * VD) + col] = __float2bfloat16(oacc[ni][p]);
        }
    }
}

// ---------------------------------------------------------------------------
extern "C" void kernel_launch(void* const* d_in, const int* in_sizes, int n_in,
                              void* d_out, int out_size, void* d_ws, size_t ws_size,
                              hipStream_t stream) {
    const float* hidden = (const float*)d_in[0];
    const float* cosb   = (const float*)d_in[1];
    const float* sinb   = (const float*)d_in[2];
    const float* Wq     = (const float*)d_in[3];
    const float* bq     = (const float*)d_in[4];
    const float* Wkva   = (const float*)d_in[5];
    const float* bkva   = (const float*)d_in[6];
    const float* Wkvb   = (const float*)d_in[7];
    const float* Wo     = (const float*)d_in[8];
    const float* bo     = (const float*)d_in[9];
    const float* sinks  = (const float*)d_in[10];
    float* out = (float*)d_out;

    // workspace carve-up (~144 MB)
    uint8_t* p = (uint8_t*)d_ws;
    __hip_bfloat16* q_bf    = (__hip_bfloat16*)p; p += (size_t)S_LEN * NQK * 2;       // 25.2 MB
    float*          ckv     = (float*)p;          p += (size_t)S_LEN * CKV_N * 4;     //  4.7 MB
    __hip_bfloat16* kn_bf   = (__hip_bfloat16*)p; p += (size_t)S_LEN * KNW * 2;       // 16.8 MB
    __hip_bfloat16* vt_bf   = (__hip_bfloat16*)p; p += (size_t)S_LEN * NH * VD * 2;   // 16.8 MB
    __hip_bfloat16* kr_bf   = (__hip_bfloat16*)p; p += (size_t)S_LEN * ROPE_D * 2;    //  0.25 MB
    __hip_bfloat16* attn_bf = (__hip_bfloat16*)p; p += (size_t)S_LEN * NH * VD * 2;   // 16.8 MB
    __hip_bfloat16* hid_bf  = (__hip_bfloat16*)p; p += (size_t)S_LEN * HID_DIM * 2;   //  8.4 MB
    __hip_bfloat16* WqT     = (__hip_bfloat16*)p; p += (size_t)NQK * HID_DIM * 2;     // 25.2 MB
    __hip_bfloat16* WkvaT   = (__hip_bfloat16*)p; p += (size_t)640 * HID_DIM * 2;     //  2.6 MB
    __hip_bfloat16* WkvbT   = (__hip_bfloat16*)p; p += (size_t)KVN * KV_RANK * 2;     //  8.4 MB
    __hip_bfloat16* WoT     = (__hip_bfloat16*)p; p += (size_t)OUT_HID * (NH*VD) * 2; // 16.8 MB
    __hip_bfloat16* kvlat   = (__hip_bfloat16*)p; p += (size_t)S_LEN * KV_RANK * 2;   //  2.1 MB

    // --- conversions ---
    cvt_bf16_kernel<<<(S_LEN * HID_DIM / 4 + 255) / 256, 256, 0, stream>>>(
        hidden, hid_bf, S_LEN * HID_DIM / 4);
    transpose_cvt<<<dim3(NQK / 32, HID_DIM / 32), 256, 0, stream>>>(Wq, WqT, HID_DIM, NQK);
    transpose_cvt<<<dim3(CKV_N / 32, HID_DIM / 32), 256, 0, stream>>>(Wkva, WkvaT, HID_DIM, CKV_N);
    transpose_cvt<<<dim3(KVN / 32, KV_RANK / 32), 256, 0, stream>>>(Wkvb, WkvbT, KV_RANK, KVN);
    transpose_cvt<<<dim3(OUT_HID / 32, (NH * VD) / 32), 256, 0, stream>>>(Wo, WoT, NH * VD, OUT_HID);

    // --- q = hidden @ Wq + bq ---
    gemm_bf16<__hip_bfloat16><<<dim3(NQK / 128, S_LEN / 128), 256, 0, stream>>>(
        hid_bf, HID_DIM, WqT, HID_DIM, bq, q_bf, NQK, HID_DIM, NQK);

    // --- ckv = hidden @ Wkva + bkva (fp32, N=576 via 5 masked tiles) ---
    gemm_bf16<float><<<dim3(5, S_LEN / 128), 256, 0, stream>>>(
        hid_bf, HID_DIM, WkvaT, HID_DIM, bkva, ckv, CKV_N, HID_DIM, CKV_N);

    // --- RoPE (q in place, k_rope -> kr_bf) ---
    rope_kernel<<<S_LEN, 256, 0, stream>>>(q_bf, ckv, kr_bf, cosb, sinb);

    // --- kv_lat -> bf16 ---
    cvt_kvlat_kernel<<<(S_LEN * KV_RANK) / 256, 256, 0, stream>>>(ckv, kvlat);

    // --- kv up-proj: kn + transposed V ---
    gemm_kv<<<dim3(KVN / 128, S_LEN / 128), 256, 0, stream>>>(
        kvlat, WkvbT, kn_bf, vt_bf);

    // --- attention (MFMA) ---
    attn_mfma_kernel<<<dim3(S_LEN / 32, NH), 256, 0, stream>>>(
        q_bf, kn_bf, kr_bf, vt_bf, sinks, attn_bf);

    // --- out = attn @ Wo + bo (fp32 out) ---
    gemm_bf16<float><<<dim3(OUT_HID / 128, S_LEN / 128), 256, 0, stream>>>(
        attn_bf, NH * VD, WoT, NH * VD, bo, out, OUT_HID, NH * VD, OUT_HID);
}

// Round 5
// 429.285 us; speedup vs baseline: 6.9261x; 1.1126x over previous
//
#include <hip/hip_runtime.h>
#include <hip/hip_bf16.h>
#include <math.h>

#define S_LEN 2048
#define HID_DIM 2048
#define NH 32
#define NOPE 128
#define ROPE_D 64
#define QKD 192           // NOPE + ROPE
#define VD 128
#define KV_RANK 512
#define SW 128
#define NQK (NH*QKD)      // 6144
#define CKV_N (KV_RANK+ROPE_D) // 576
#define KVN (NH*(NOPE+VD))     // 8192
#define KNW (NH*NOPE)          // 4096
#define OUT_HID 2048
#define ATT_SCALE 0.07216878364870323f  // 192^-0.5
#define NEG_INF (-1e30f)

typedef __bf16 bf16x8 __attribute__((ext_vector_type(8)));
typedef float  f32x4  __attribute__((ext_vector_type(4)));

// ---------------------------------------------------------------------------
// async global->LDS, 16B per lane. LDS dest = wave-uniform base + lane*16.
// ---------------------------------------------------------------------------
__device__ __forceinline__ void async_load16(const void* gp, void* lp) {
    __builtin_amdgcn_global_load_lds(
        (const __attribute__((address_space(1))) void*)gp,
        (__attribute__((address_space(3))) void*)lp, 16, 0, 0);
}

// ---------------------------------------------------------------------------
// prep: merged fp32->bf16 conversions. blockIdx ranges:
//   [0,4096)          hidden -> hid_bf (elementwise, float4)
//   [4096,16384)      Wq   [2048x6144] -> WqT   [6144][2048]
//   [16384,17536)     Wkva [2048x576]  -> WkvaT [576][2048] (alloc 640 rows)
//   [17536,21632)     Wkvb [512x8192]  -> WkvbT [8192][512]
//   [21632,29824)     Wo   [4096x2048] -> WoT   [2048][4096]
// ---------------------------------------------------------------------------
__global__ __launch_bounds__(256)
void prep(const float* __restrict__ hidden, __hip_bfloat16* __restrict__ hid_bf,
          const float* __restrict__ Wq,   __hip_bfloat16* __restrict__ WqT,
          const float* __restrict__ Wkva, __hip_bfloat16* __restrict__ WkvaT,
          const float* __restrict__ Wkvb, __hip_bfloat16* __restrict__ WkvbT,
          const float* __restrict__ Wo,   __hip_bfloat16* __restrict__ WoT)
{
    __shared__ float tile[32][33];
    int b = blockIdx.x;
    const int t = threadIdx.x;

    if (b < 4096) {
        int i = b * 256 + t;            // float4 index over 2048*2048/4
        float4 v = ((const float4*)hidden)[i];
        hid_bf[i * 4 + 0] = __float2bfloat16(v.x);
        hid_bf[i * 4 + 1] = __float2bfloat16(v.y);
        hid_bf[i * 4 + 2] = __float2bfloat16(v.z);
        hid_bf[i * 4 + 3] = __float2bfloat16(v.w);
        return;
    }
    b -= 4096;
    const float* src; __hip_bfloat16* dst; int rows, cols, CX;
    if (b < 12288)        { src = Wq;   dst = WqT;   rows = 2048; cols = 6144; CX = 192; }
    else if ((b -= 12288) < 1152)  { src = Wkva; dst = WkvaT; rows = 2048; cols = 576;  CX = 18;  }
    else if ((b -= 1152) < 4096)   { src = Wkvb; dst = WkvbT; rows = 512;  cols = 8192; CX = 256; }
    else { b -= 4096;       src = Wo;   dst = WoT;   rows = 4096; cols = 2048; CX = 64;  }

    const int bx = b % CX, by = b / CX;
    const int r0 = by * 32, c0 = bx * 32;
    const int tx = t & 31, ty = t >> 5;
    #pragma unroll
    for (int i = 0; i < 4; ++i)
        tile[ty + i * 8][tx] = src[(size_t)(r0 + ty + i * 8) * cols + c0 + tx];
    __syncthreads();
    #pragma unroll
    for (int i = 0; i < 4; ++i)
        dst[(size_t)(c0 + ty + i * 8) * rows + r0 + tx] = __float2bfloat16(tile[tx][ty + i * 8]);
}

// ---------------------------------------------------------------------------
// Wq GEMM with fused bias + q-RoPE epilogue. C bf16 [2048][6144].
// Rope cols for head h: [192h+128,192h+192) fall wholly in tile bx with
// bx%3==1 (offset 0..63, wave-half wn=0) or bx%3==2 (offset 64..127, wn=64).
// Pair (dd, dd+32) lives in same lane: acc[mi][ni] <-> acc[mi][ni+2].
// ---------------------------------------------------------------------------
__global__ __launch_bounds__(256)
void gemm_q(const __hip_bfloat16* __restrict__ A,
            const __hip_bfloat16* __restrict__ Bt,
            const float* __restrict__ bias,
            const float* __restrict__ cosb, const float* __restrict__ sinb,
            __hip_bfloat16* __restrict__ C)
{
    __shared__ __hip_bfloat16 As[128 * 32];
    __shared__ __hip_bfloat16 Bs[128 * 32];

    const int t = threadIdx.x;
    const int w = t >> 6;
    const int L = t & 63;
    const int lane15 = L & 15, quad = L >> 4;
    const int wm = (w & 1) * 64, wn = (w >> 1) * 64;
    const int m0 = blockIdx.y * 128;
    const int n0 = blockIdx.x * 128;

    f32x4 acc[4][4];
    #pragma unroll
    for (int mi = 0; mi < 4; ++mi)
        #pragma unroll
        for (int ni = 0; ni < 4; ++ni)
            acc[mi][ni] = (f32x4){0.f, 0.f, 0.f, 0.f};

    for (int k0 = 0; k0 < HID_DIM; k0 += 32) {
        __syncthreads();
        #pragma unroll
        for (int i = 0; i < 2; ++i) {
            const int slot = w * 64 + i * 256 + L;
            const int base = (w * 64 + i * 256) * 8;
            async_load16(A  + (size_t)(m0 + (slot >> 2)) * HID_DIM + k0 + (slot & 3) * 8,
                         (void*)(As + base));
            async_load16(Bt + (size_t)(n0 + (slot >> 2)) * HID_DIM + k0 + (slot & 3) * 8,
                         (void*)(Bs + base));
        }
        __syncthreads();

        bf16x8 af[4], bfr[4];
        #pragma unroll
        for (int mi = 0; mi < 4; ++mi)
            af[mi] = *(const bf16x8*)(const void*)(As + (wm + mi * 16 + lane15) * 32 + quad * 8);
        #pragma unroll
        for (int ni = 0; ni < 4; ++ni)
            bfr[ni] = *(const bf16x8*)(const void*)(Bs + (wn + ni * 16 + lane15) * 32 + quad * 8);
        #pragma unroll
        for (int mi = 0; mi < 4; ++mi)
            #pragma unroll
            for (int ni = 0; ni < 4; ++ni)
                acc[mi][ni] = __builtin_amdgcn_mfma_f32_16x16x32_bf16(af[mi], bfr[ni], acc[mi][ni], 0, 0, 0);
    }

    const int bxm3 = blockIdx.x % 3;
    const bool do_rope = (bxm3 == 1 && wn == 0) || (bxm3 == 2 && wn == 64);

    #pragma unroll
    for (int mi = 0; mi < 4; ++mi) {
        const int rbase = m0 + wm + mi * 16 + quad * 4;
        float vv[4][4];
        #pragma unroll
        for (int ni = 0; ni < 4; ++ni) {
            const float bv = bias[n0 + wn + ni * 16 + lane15];
            #pragma unroll
            for (int p = 0; p < 4; ++p) vv[ni][p] = acc[mi][ni][p] + bv;
        }
        if (do_rope) {
            #pragma unroll
            for (int ni = 0; ni < 2; ++ni) {
                const int dd = ni * 16 + lane15;
                #pragma unroll
                for (int p = 0; p < 4; ++p) {
                    const int srow = rbase + p;
                    const float c0 = cosb[srow * ROPE_D + dd];
                    const float c1 = cosb[srow * ROPE_D + dd + 32];
                    const float s0 = sinb[srow * ROPE_D + dd];
                    const float s1 = sinb[srow * ROPE_D + dd + 32];
                    const float x0 = vv[ni][p], x1 = vv[ni + 2][p];
                    vv[ni][p]     = x0 * c0 - x1 * s0;
                    vv[ni + 2][p] = x1 * c1 + x0 * s1;
                }
            }
        }
        #pragma unroll
        for (int ni = 0; ni < 4; ++ni) {
            const int c = n0 + wn + ni * 16 + lane15;
            #pragma unroll
            for (int p = 0; p < 4; ++p)
                C[(size_t)(rbase + p) * NQK + c] = __float2bfloat16(vv[ni][p]);
        }
    }
}

// ---------------------------------------------------------------------------
// Split-K bf16 MFMA GEMM writing fp32 partials: P[z][M][ldp].
// blockIdx.z selects K-slice [z*KL, (z+1)*KL). No bias.
// ---------------------------------------------------------------------------
__global__ __launch_bounds__(256)
void gemm_partial(const __hip_bfloat16* __restrict__ A, int lda,
                  const __hip_bfloat16* __restrict__ Bt, int ldbt,
                  float* __restrict__ P, int ldp, size_t zstride, int KL)
{
    __shared__ __hip_bfloat16 As[128 * 32];
    __shared__ __hip_bfloat16 Bs[128 * 32];

    const int t = threadIdx.x;
    const int w = t >> 6;
    const int L = t & 63;
    const int lane15 = L & 15, quad = L >> 4;
    const int wm = (w & 1) * 64, wn = (w >> 1) * 64;
    const int m0 = blockIdx.y * 128;
    const int n0 = blockIdx.x * 128;
    const int z  = blockIdx.z;
    float* Pz = P + (size_t)z * zstride;

    f32x4 acc[4][4];
    #pragma unroll
    for (int mi = 0; mi < 4; ++mi)
        #pragma unroll
        for (int ni = 0; ni < 4; ++ni)
            acc[mi][ni] = (f32x4){0.f, 0.f, 0.f, 0.f};

    const int kend = (z + 1) * KL;
    for (int k0 = z * KL; k0 < kend; k0 += 32) {
        __syncthreads();
        #pragma unroll
        for (int i = 0; i < 2; ++i) {
            const int slot = w * 64 + i * 256 + L;
            const int base = (w * 64 + i * 256) * 8;
            async_load16(A  + (size_t)(m0 + (slot >> 2)) * lda  + k0 + (slot & 3) * 8,
                         (void*)(As + base));
            async_load16(Bt + (size_t)(n0 + (slot >> 2)) * ldbt + k0 + (slot & 3) * 8,
                         (void*)(Bs + base));
        }
        __syncthreads();

        bf16x8 af[4], bfr[4];
        #pragma unroll
        for (int mi = 0; mi < 4; ++mi)
            af[mi] = *(const bf16x8*)(const void*)(As + (wm + mi * 16 + lane15) * 32 + quad * 8);
        #pragma unroll
        for (int ni = 0; ni < 4; ++ni)
            bfr[ni] = *(const bf16x8*)(const void*)(Bs + (wn + ni * 16 + lane15) * 32 + quad * 8);
        #pragma unroll
        for (int mi = 0; mi < 4; ++mi)
            #pragma unroll
            for (int ni = 0; ni < 4; ++ni)
                acc[mi][ni] = __builtin_amdgcn_mfma_f32_16x16x32_bf16(af[mi], bfr[ni], acc[mi][ni], 0, 0, 0);
    }

    #pragma unroll
    for (int mi = 0; mi < 4; ++mi) {
        const int rbase = m0 + wm + mi * 16 + quad * 4;
        #pragma unroll
        for (int ni = 0; ni < 4; ++ni) {
            const int c = n0 + wn + ni * 16 + lane15;
            #pragma unroll
            for (int p = 0; p < 4; ++p)
                Pz[(size_t)(rbase + p) * ldp + c] = acc[mi][ni][p];
        }
    }
}

// ---------------------------------------------------------------------------
// ckv reduce: sum 4 K-partials [2048][640] + bkva; cols<512 -> kvlat bf16;
// cols 512..575 -> RoPE -> kr bf16. One block per row s.
// ---------------------------------------------------------------------------
__global__ __launch_bounds__(256)
void ckv_reduce(const float* __restrict__ P, const float* __restrict__ bkva,
                __hip_bfloat16* __restrict__ kvlat, __hip_bfloat16* __restrict__ kr,
                const float* __restrict__ cosb, const float* __restrict__ sinb)
{
    const int s = blockIdx.x;
    const int t = threadIdx.x;
    const size_t zs = (size_t)S_LEN * 640;
    const float* row = P + (size_t)s * 640;

    for (int c = t; c < KV_RANK; c += 256) {
        float v = row[c] + row[zs + c] + row[2 * zs + c] + row[3 * zs + c] + bkva[c];
        kvlat[(size_t)s * KV_RANK + c] = __float2bfloat16(v);
    }
    if (t < 32) {
        const int d = t;
        float a = row[512 + d] + row[zs + 512 + d] + row[2 * zs + 512 + d] + row[3 * zs + 512 + d] + bkva[512 + d];
        float b = row[544 + d] + row[zs + 544 + d] + row[2 * zs + 544 + d] + row[3 * zs + 544 + d] + bkva[544 + d];
        const float c0 = cosb[s * ROPE_D + d],      c1 = cosb[s * ROPE_D + d + 32];
        const float s0 = sinb[s * ROPE_D + d],      s1 = sinb[s * ROPE_D + d + 32];
        kr[(size_t)s * ROPE_D + d]      = __float2bfloat16(a * c0 - b * s0);
        kr[(size_t)s * ROPE_D + d + 32] = __float2bfloat16(b * c1 + a * s1);
    }
}

// ---------------------------------------------------------------------------
// Wo reduce: out = P0 + P1 + bo  (fp32, float4).
// ---------------------------------------------------------------------------
__global__ __launch_bounds__(256)
void wo_reduce(const float* __restrict__ P, const float* __restrict__ bo,
               float* __restrict__ out)
{
    const size_t i = (size_t)blockIdx.x * 256 + threadIdx.x;  // float4 index
    const size_t zs = (size_t)S_LEN * OUT_HID;
    float4 a = ((const float4*)P)[i];
    float4 b = ((const float4*)(P + zs))[i];
    const int col = (int)((i * 4) & (OUT_HID - 1));
    float4 bb = *(const float4*)(bo + col);
    float4 o;
    o.x = a.x + b.x + bb.x; o.y = a.y + b.y + bb.y;
    o.z = a.z + b.z + bb.z; o.w = a.w + b.w + bb.w;
    ((float4*)out)[i] = o;
}

// ---------------------------------------------------------------------------
// kv up-proj GEMM with split epilogue: kn [s][4096] + transposed V [4096][s].
// ---------------------------------------------------------------------------
__global__ __launch_bounds__(256)
void gemm_kv(const __hip_bfloat16* __restrict__ A,
             const __hip_bfloat16* __restrict__ Bt,
             __hip_bfloat16* __restrict__ kn,
             __hip_bfloat16* __restrict__ vt)
{
    __shared__ __hip_bfloat16 As[128 * 32];
    __shared__ __hip_bfloat16 Bs[128 * 32];

    const int t = threadIdx.x;
    const int w = t >> 6;
    const int L = t & 63;
    const int lane15 = L & 15, quad = L >> 4;
    const int wm = (w & 1) * 64, wn = (w >> 1) * 64;
    const int m0 = blockIdx.y * 128;
    const int n0 = blockIdx.x * 128;

    f32x4 acc[4][4];
    #pragma unroll
    for (int mi = 0; mi < 4; ++mi)
        #pragma unroll
        for (int ni = 0; ni < 4; ++ni)
            acc[mi][ni] = (f32x4){0.f, 0.f, 0.f, 0.f};

    for (int k0 = 0; k0 < KV_RANK; k0 += 32) {
        __syncthreads();
        #pragma unroll
        for (int i = 0; i < 2; ++i) {
            const int slot = w * 64 + i * 256 + L;
            const int base = (w * 64 + i * 256) * 8;
            async_load16(A  + (size_t)(m0 + (slot >> 2)) * KV_RANK + k0 + (slot & 3) * 8,
                         (void*)(As + base));
            async_load16(Bt + (size_t)(n0 + (slot >> 2)) * KV_RANK + k0 + (slot & 3) * 8,
                         (void*)(Bs + base));
        }
        __syncthreads();

        bf16x8 af[4], bfr[4];
        #pragma unroll
        for (int mi = 0; mi < 4; ++mi)
            af[mi] = *(const bf16x8*)(const void*)(As + (wm + mi * 16 + lane15) * 32 + quad * 8);
        #pragma unroll
        for (int ni = 0; ni < 4; ++ni)
            bfr[ni] = *(const bf16x8*)(const void*)(Bs + (wn + ni * 16 + lane15) * 32 + quad * 8);
        #pragma unroll
        for (int mi = 0; mi < 4; ++mi)
            #pragma unroll
            for (int ni = 0; ni < 4; ++ni)
                acc[mi][ni] = __builtin_amdgcn_mfma_f32_16x16x32_bf16(af[mi], bfr[ni], acc[mi][ni], 0, 0, 0);
    }

    #pragma unroll
    for (int mi = 0; mi < 4; ++mi) {
        const int rbase = m0 + wm + mi * 16 + quad * 4;
        #pragma unroll
        for (int ni = 0; ni < 4; ++ni) {
            const int c = n0 + wn + ni * 16 + lane15;
            const int h = c >> 8, d = c & 255;
            if (d < NOPE) {
                #pragma unroll
                for (int p = 0; p < 4; ++p)
                    kn[(size_t)(rbase + p) * KNW + h * NOPE + d] = __float2bfloat16(acc[mi][ni][p]);
            } else {
                ushort4 pk;
                __hip_bfloat16 b0 = __float2bfloat16(acc[mi][ni][0]);
                __hip_bfloat16 b1 = __float2bfloat16(acc[mi][ni][1]);
                __hip_bfloat16 b2 = __float2bfloat16(acc[mi][ni][2]);
                __hip_bfloat16 b3 = __float2bfloat16(acc[mi][ni][3]);
                pk.x = *(unsigned short*)&b0; pk.y = *(unsigned short*)&b1;
                pk.z = *(unsigned short*)&b2; pk.w = *(unsigned short*)&b3;
                *(ushort4*)(vt + (size_t)(h * VD + (d - NOPE)) * S_LEN + rbase) = pk;
            }
        }
    }
}

// ---------------------------------------------------------------------------
// MFMA sliding-window attention with sink (unchanged from round 4).
// ---------------------------------------------------------------------------
#define SS 170
#define SP 168

__global__ __launch_bounds__(256)
void attn_mfma_kernel(const __hip_bfloat16* __restrict__ q,
                      const __hip_bfloat16* __restrict__ kn,
                      const __hip_bfloat16* __restrict__ kr,
                      const __hip_bfloat16* __restrict__ vt,
                      const float* __restrict__ sinks,
                      __hip_bfloat16* __restrict__ out)
{
    __shared__ float lds_s[32 * SS];
    __shared__ __hip_bfloat16 lds_p[32 * SP];

    const int h  = blockIdx.y;
    const int q0 = blockIdx.x * 32;
    const int t  = threadIdx.x;
    const int w  = t >> 6;
    const int L  = t & 63;
    const int lane15 = L & 15, quad = L >> 4;
    const int wm = (w & 1) * 16;

    int lo = q0 - SW + 1; if (lo < 0) lo = 0;
    const int cb = lo & ~31;
    const int nc = ((q0 - cb) >> 5) + 1;    // 1..5

    bf16x8 qf[6];
    {
        const __hip_bfloat16* qrow = q + (size_t)(q0 + wm + lane15) * NQK + h * QKD;
        #pragma unroll
        for (int kk = 0; kk < 6; ++kk)
            qf[kk] = *(const bf16x8*)(const void*)(qrow + kk * 32 + quad * 8);
    }

    {
        const int wn = (w >> 1) * 16;
        for (int cc = 0; cc < nc; ++cc) {
            const int kbase = cb + cc * 32 + wn;
            const __hip_bfloat16* knrow = kn + (size_t)(kbase + lane15) * KNW + h * NOPE;
            const __hip_bfloat16* krrow = kr + (size_t)(kbase + lane15) * ROPE_D;
            f32x4 s = (f32x4){0.f, 0.f, 0.f, 0.f};
            #pragma unroll
            for (int kk = 0; kk < 4; ++kk) {
                bf16x8 bf = *(const bf16x8*)(const void*)(knrow + kk * 32 + quad * 8);
                s = __builtin_amdgcn_mfma_f32_16x16x32_bf16(qf[kk], bf, s, 0, 0, 0);
            }
            #pragma unroll
            for (int kk = 0; kk < 2; ++kk) {
                bf16x8 bf = *(const bf16x8*)(const void*)(krrow + kk * 32 + quad * 8);
                s = __builtin_amdgcn_mfma_f32_16x16x32_bf16(qf[4 + kk], bf, s, 0, 0, 0);
            }
            const int j = kbase + lane15;
            #pragma unroll
            for (int p = 0; p < 4; ++p) {
                const int i = q0 + wm + quad * 4 + p;
                const bool ok = (j <= i) && (i - j < SW);
                lds_s[(wm + quad * 4 + p) * SS + cc * 32 + wn + lane15] =
                    ok ? s[p] * ATT_SCALE : NEG_INF;
            }
        }
    }
    __syncthreads();

    {
        const int r = t >> 3, g = t & 7;
        const int ncols = nc * 32;
        const float sink = sinks[h];
        float mx = sink;
        for (int c = g; c < ncols; c += 8)
            mx = fmaxf(mx, lds_s[r * SS + c]);
        #pragma unroll
        for (int off = 1; off < 8; off <<= 1)
            mx = fmaxf(mx, __shfl_xor(mx, off));
        float sum = 0.f;
        for (int c = g; c < ncols; c += 8) {
            float e = __expf(lds_s[r * SS + c] - mx);
            lds_s[r * SS + c] = e;
            sum += e;
        }
        #pragma unroll
        for (int off = 1; off < 8; off <<= 1)
            sum += __shfl_xor(sum, off);
        const float inv = 1.0f / (sum + __expf(sink - mx));
        for (int c = g; c < ncols; c += 8)
            lds_p[r * SP + c] = __float2bfloat16(lds_s[r * SS + c] * inv);
    }
    __syncthreads();

    f32x4 oacc[4];
    #pragma unroll
    for (int ni = 0; ni < 4; ++ni) oacc[ni] = (f32x4){0.f, 0.f, 0.f, 0.f};
    const int vrow0 = h * VD + (w >> 1) * 64;
    for (int cc = 0; cc < nc; ++cc) {
        bf16x8 ap = *(const bf16x8*)(const void*)(lds_p + (wm + lane15) * SP + cc * 32 + quad * 8);
        const int koff = cb + cc * 32 + quad * 8;
        #pragma unroll
        for (int ni = 0; ni < 4; ++ni) {
            bf16x8 bv = *(const bf16x8*)(const void*)(vt + (size_t)(vrow0 + ni * 16 + lane15) * S_LEN + koff);
            oacc[ni] = __builtin_amdgcn_mfma_f32_16x16x32_bf16(ap, bv, oacc[ni], 0, 0, 0);
        }
    }

    #pragma unroll
    for (int ni = 0; ni < 4; ++ni) {
        const int col = h * VD + (w >> 1) * 64 + ni * 16 + lane15;
        #pragma unroll
        for (int p = 0; p < 4; ++p) {
            const int row = q0 + wm + quad * 4 + p;
            out[(size_t)row * (NH * VD) + col] = __float2bfloat16(oacc[ni][p]);
        }
    }
}

// ---------------------------------------------------------------------------
extern "C" void kernel_launch(void* const* d_in, const int* in_sizes, int n_in,
                              void* d_out, int out_size, void* d_ws, size_t ws_size,
                              hipStream_t stream) {
    const float* hidden = (const float*)d_in[0];
    const float* cosb   = (const float*)d_in[1];
    const float* sinb   = (const float*)d_in[2];
    const float* Wq     = (const float*)d_in[3];
    const float* bq     = (const float*)d_in[4];
    const float* Wkva   = (const float*)d_in[5];
    const float* bkva   = (const float*)d_in[6];
    const float* Wkvb   = (const float*)d_in[7];
    const float* Wo     = (const float*)d_in[8];
    const float* bo     = (const float*)d_in[9];
    const float* sinks  = (const float*)d_in[10];
    float* out = (float*)d_out;

    // workspace carve-up, 143.4 MB total (<144.05 proven in round 3).
    // Aliases: WoP <- (q_bf+hid_bf) [dead after attn]; ckvP <-> attn_bf
    // [ckvP dead after ckv_reduce, attn_bf written at attn].
    uint8_t* p = (uint8_t*)d_ws;
    __hip_bfloat16* q_bf    = (__hip_bfloat16*)p; p += (size_t)S_LEN * NQK * 2;       // 25.2 MB
    __hip_bfloat16* hid_bf  = (__hip_bfloat16*)p; p += (size_t)S_LEN * HID_DIM * 2;   //  8.4 MB
    float*          WoP     = (float*)q_bf;       // 2 x 2048 x 2048 fp32 = 33.55 MB (alias)
    uint8_t*        regionB = p;                  p += (size_t)4 * S_LEN * 640 * 4;   // 21.0 MB
    float*          ckvP    = (float*)regionB;
    __hip_bfloat16* attn_bf = (__hip_bfloat16*)regionB;   // 16.8 MB (alias)
    __hip_bfloat16* kn_bf   = (__hip_bfloat16*)p; p += (size_t)S_LEN * KNW * 2;       // 16.8 MB
    __hip_bfloat16* vt_bf   = (__hip_bfloat16*)p; p += (size_t)S_LEN * NH * VD * 2;   // 16.8 MB
    __hip_bfloat16* kr_bf   = (__hip_bfloat16*)p; p += (size_t)S_LEN * ROPE_D * 2;    //  0.25 MB
    __hip_bfloat16* kvlat   = (__hip_bfloat16*)p; p += (size_t)S_LEN * KV_RANK * 2;   //  2.1 MB
    __hip_bfloat16* WqT     = (__hip_bfloat16*)p; p += (size_t)NQK * HID_DIM * 2;     // 25.2 MB
    __hip_bfloat16* WkvaT   = (__hip_bfloat16*)p; p += (size_t)640 * HID_DIM * 2;     //  2.6 MB
    __hip_bfloat16* WkvbT   = (__hip_bfloat16*)p; p += (size_t)KVN * KV_RANK * 2;     //  8.4 MB
    __hip_bfloat16* WoT     = (__hip_bfloat16*)p; p += (size_t)OUT_HID * (NH*VD) * 2; // 16.8 MB

    // 1. merged conversions (hidden cvt + 4 weight transposes)
    prep<<<29824, 256, 0, stream>>>(hidden, hid_bf, Wq, WqT, Wkva, WkvaT,
                                    Wkvb, WkvbT, Wo, WoT);

    // 2. q = hidden @ Wq + bq, RoPE fused in epilogue
    gemm_q<<<dim3(NQK / 128, S_LEN / 128), 256, 0, stream>>>(
        hid_bf, WqT, bq, cosb, sinb, q_bf);

    // 3. ckv partials: split-K x4 (grid 5x16x4 = 320 blocks)
    gemm_partial<<<dim3(5, S_LEN / 128, 4), 256, 0, stream>>>(
        hid_bf, HID_DIM, WkvaT, HID_DIM, ckvP, 640, (size_t)S_LEN * 640, 512);

    // 4. reduce + bias + kvlat bf16 + k-RoPE
    ckv_reduce<<<S_LEN, 256, 0, stream>>>(ckvP, bkva, kvlat, kr_bf, cosb, sinb);

    // 5. kv up-proj: kn + transposed V
    gemm_kv<<<dim3(KVN / 128, S_LEN / 128), 256, 0, stream>>>(
        kvlat, WkvbT, kn_bf, vt_bf);

    // 6. attention (MFMA)
    attn_mfma_kernel<<<dim3(S_LEN / 32, NH), 256, 0, stream>>>(
        q_bf, kn_bf, kr_bf, vt_bf, sinks, attn_bf);

    // 7. Wo partials: split-K x2 (grid 16x16x2 = 512 blocks)
    gemm_partial<<<dim3(OUT_HID / 128, S_LEN / 128, 2), 256, 0, stream>>>(
        attn_bf, NH * VD, WoT, NH * VD, WoP, OUT_HID, (size_t)S_LEN * OUT_HID, 2048);

    // 8. out = P0 + P1 + bo
    wo_reduce<<<(S_LEN * OUT_HID / 4) / 256, 256, 0, stream>>>(WoP, bo, out);
}

// Round 6
// 423.676 us; speedup vs baseline: 7.0178x; 1.0132x over previous
//
#include <hip/hip_runtime.h>
#include <hip/hip_bf16.h>
#include <math.h>

#define S_LEN 2048
#define HID_DIM 2048
#define NH 32
#define NOPE 128
#define ROPE_D 64
#define QKD 192           // NOPE + ROPE
#define VD 128
#define KV_RANK 512
#define SW 128
#define NQK (NH*QKD)      // 6144
#define CKV_N (KV_RANK+ROPE_D) // 576
#define KVN (NH*(NOPE+VD))     // 8192
#define KNW (NH*NOPE)          // 4096
#define OUT_HID 2048
#define ATT_SCALE 0.07216878364870323f  // 192^-0.5
#define NEG_INF (-1e30f)

typedef __bf16 bf16x8 __attribute__((ext_vector_type(8)));
typedef float  f32x4  __attribute__((ext_vector_type(4)));

// ---------------------------------------------------------------------------
// async global->LDS, 16B per lane. LDS dest = wave-uniform base + lane*16.
// ---------------------------------------------------------------------------
__device__ __forceinline__ void async_load16(const void* gp, void* lp) {
    __builtin_amdgcn_global_load_lds(
        (const __attribute__((address_space(1))) void*)gp,
        (__attribute__((address_space(3))) void*)lp, 16, 0, 0);
}

// ---------------------------------------------------------------------------
// prep: merged fp32->bf16 conversions. 64x64 transpose tiles (128B stores).
//   [0,4096)      hidden -> hid_bf (elementwise float4)
//   [4096,+3072)  Wq   [2048x6144] -> WqT   [6144][2048]
//   [+288)        Wkva [2048x576]  -> WkvaT [576][2048]
//   [+1024)       Wkvb [512x8192]  -> WkvbT [8192][512]
//   [+2048)       Wo   [4096x2048] -> WoT   [2048][4096]
// ---------------------------------------------------------------------------
__global__ __launch_bounds__(256)
void prep(const float* __restrict__ hidden, __hip_bfloat16* __restrict__ hid_bf,
          const float* __restrict__ Wq,   __hip_bfloat16* __restrict__ WqT,
          const float* __restrict__ Wkva, __hip_bfloat16* __restrict__ WkvaT,
          const float* __restrict__ Wkvb, __hip_bfloat16* __restrict__ WkvbT,
          const float* __restrict__ Wo,   __hip_bfloat16* __restrict__ WoT)
{
    __shared__ float tile[64][65];
    int b = blockIdx.x;
    const int t = threadIdx.x;

    if (b < 4096) {
        int i = b * 256 + t;
        float4 v = ((const float4*)hidden)[i];
        hid_bf[i * 4 + 0] = __float2bfloat16(v.x);
        hid_bf[i * 4 + 1] = __float2bfloat16(v.y);
        hid_bf[i * 4 + 2] = __float2bfloat16(v.z);
        hid_bf[i * 4 + 3] = __float2bfloat16(v.w);
        return;
    }
    b -= 4096;
    const float* src; __hip_bfloat16* dst; int rows, cols, CX;
    if (b < 3072)                { src = Wq;   dst = WqT;   rows = 2048; cols = 6144; CX = 96;  }
    else if ((b -= 3072) < 288)  { src = Wkva; dst = WkvaT; rows = 2048; cols = 576;  CX = 9;   }
    else if ((b -= 288) < 1024)  { src = Wkvb; dst = WkvbT; rows = 512;  cols = 8192; CX = 128; }
    else { b -= 1024;              src = Wo;   dst = WoT;   rows = 4096; cols = 2048; CX = 32;  }

    const int bx = b % CX, by = b / CX;
    const int r0 = by * 64, c0 = bx * 64;
    const int tx = t & 63, ty = t >> 6;   // ty 0..3
    #pragma unroll
    for (int i = 0; i < 16; ++i) {
        const int rr = ty + i * 4;
        tile[rr][tx] = src[(size_t)(r0 + rr) * cols + c0 + tx];
    }
    __syncthreads();
    #pragma unroll
    for (int i = 0; i < 16; ++i) {
        const int dr = ty + i * 4;
        dst[(size_t)(c0 + dr) * rows + r0 + tx] = __float2bfloat16(tile[tx][dr]);
    }
}

// ---------------------------------------------------------------------------
// Wq GEMM, fused bias + q-RoPE + ATT_SCALE epilogue. C bf16 [2048][6144].
// q_bf is consumed ONLY by attention, so the softmax scale is folded here.
// ---------------------------------------------------------------------------
__global__ __launch_bounds__(256)
void gemm_q(const __hip_bfloat16* __restrict__ A,
            const __hip_bfloat16* __restrict__ Bt,
            const float* __restrict__ bias,
            const float* __restrict__ cosb, const float* __restrict__ sinb,
            __hip_bfloat16* __restrict__ C)
{
    __shared__ __hip_bfloat16 As[128 * 32];
    __shared__ __hip_bfloat16 Bs[128 * 32];

    const int t = threadIdx.x;
    const int w = t >> 6;
    const int L = t & 63;
    const int lane15 = L & 15, quad = L >> 4;
    const int wm = (w & 1) * 64, wn = (w >> 1) * 64;
    const int m0 = blockIdx.y * 128;
    const int n0 = blockIdx.x * 128;

    f32x4 acc[4][4];
    #pragma unroll
    for (int mi = 0; mi < 4; ++mi)
        #pragma unroll
        for (int ni = 0; ni < 4; ++ni)
            acc[mi][ni] = (f32x4){0.f, 0.f, 0.f, 0.f};

    for (int k0 = 0; k0 < HID_DIM; k0 += 32) {
        __syncthreads();
        #pragma unroll
        for (int i = 0; i < 2; ++i) {
            const int slot = w * 64 + i * 256 + L;
            const int base = (w * 64 + i * 256) * 8;
            async_load16(A  + (size_t)(m0 + (slot >> 2)) * HID_DIM + k0 + (slot & 3) * 8,
                         (void*)(As + base));
            async_load16(Bt + (size_t)(n0 + (slot >> 2)) * HID_DIM + k0 + (slot & 3) * 8,
                         (void*)(Bs + base));
        }
        __syncthreads();

        bf16x8 af[4], bfr[4];
        #pragma unroll
        for (int mi = 0; mi < 4; ++mi)
            af[mi] = *(const bf16x8*)(const void*)(As + (wm + mi * 16 + lane15) * 32 + quad * 8);
        #pragma unroll
        for (int ni = 0; ni < 4; ++ni)
            bfr[ni] = *(const bf16x8*)(const void*)(Bs + (wn + ni * 16 + lane15) * 32 + quad * 8);
        #pragma unroll
        for (int mi = 0; mi < 4; ++mi)
            #pragma unroll
            for (int ni = 0; ni < 4; ++ni)
                acc[mi][ni] = __builtin_amdgcn_mfma_f32_16x16x32_bf16(af[mi], bfr[ni], acc[mi][ni], 0, 0, 0);
    }

    const int bxm3 = blockIdx.x % 3;
    const bool do_rope = (bxm3 == 1 && wn == 0) || (bxm3 == 2 && wn == 64);

    #pragma unroll
    for (int mi = 0; mi < 4; ++mi) {
        const int rbase = m0 + wm + mi * 16 + quad * 4;
        float vv[4][4];
        #pragma unroll
        for (int ni = 0; ni < 4; ++ni) {
            const float bv = bias[n0 + wn + ni * 16 + lane15];
            #pragma unroll
            for (int p = 0; p < 4; ++p) vv[ni][p] = acc[mi][ni][p] + bv;
        }
        if (do_rope) {
            #pragma unroll
            for (int ni = 0; ni < 2; ++ni) {
                const int dd = ni * 16 + lane15;
                #pragma unroll
                for (int p = 0; p < 4; ++p) {
                    const int srow = rbase + p;
                    const float c0 = cosb[srow * ROPE_D + dd];
                    const float c1 = cosb[srow * ROPE_D + dd + 32];
                    const float s0 = sinb[srow * ROPE_D + dd];
                    const float s1 = sinb[srow * ROPE_D + dd + 32];
                    const float x0 = vv[ni][p], x1 = vv[ni + 2][p];
                    vv[ni][p]     = x0 * c0 - x1 * s0;
                    vv[ni + 2][p] = x1 * c1 + x0 * s1;
                }
            }
        }
        #pragma unroll
        for (int ni = 0; ni < 4; ++ni) {
            const int c = n0 + wn + ni * 16 + lane15;
            #pragma unroll
            for (int p = 0; p < 4; ++p)
                C[(size_t)(rbase + p) * NQK + c] = __float2bfloat16(vv[ni][p] * ATT_SCALE);
        }
    }
}

// ---------------------------------------------------------------------------
// Split-K bf16 MFMA GEMM writing fp32 partials: P[z][M][ldp].
// ---------------------------------------------------------------------------
__global__ __launch_bounds__(256)
void gemm_partial(const __hip_bfloat16* __restrict__ A, int lda,
                  const __hip_bfloat16* __restrict__ Bt, int ldbt,
                  float* __restrict__ P, int ldp, size_t zstride, int KL)
{
    __shared__ __hip_bfloat16 As[128 * 32];
    __shared__ __hip_bfloat16 Bs[128 * 32];

    const int t = threadIdx.x;
    const int w = t >> 6;
    const int L = t & 63;
    const int lane15 = L & 15, quad = L >> 4;
    const int wm = (w & 1) * 64, wn = (w >> 1) * 64;
    const int m0 = blockIdx.y * 128;
    const int n0 = blockIdx.x * 128;
    const int z  = blockIdx.z;
    float* Pz = P + (size_t)z * zstride;

    f32x4 acc[4][4];
    #pragma unroll
    for (int mi = 0; mi < 4; ++mi)
        #pragma unroll
        for (int ni = 0; ni < 4; ++ni)
            acc[mi][ni] = (f32x4){0.f, 0.f, 0.f, 0.f};

    const int kend = (z + 1) * KL;
    for (int k0 = z * KL; k0 < kend; k0 += 32) {
        __syncthreads();
        #pragma unroll
        for (int i = 0; i < 2; ++i) {
            const int slot = w * 64 + i * 256 + L;
            const int base = (w * 64 + i * 256) * 8;
            async_load16(A  + (size_t)(m0 + (slot >> 2)) * lda  + k0 + (slot & 3) * 8,
                         (void*)(As + base));
            async_load16(Bt + (size_t)(n0 + (slot >> 2)) * ldbt + k0 + (slot & 3) * 8,
                         (void*)(Bs + base));
        }
        __syncthreads();

        bf16x8 af[4], bfr[4];
        #pragma unroll
        for (int mi = 0; mi < 4; ++mi)
            af[mi] = *(const bf16x8*)(const void*)(As + (wm + mi * 16 + lane15) * 32 + quad * 8);
        #pragma unroll
        for (int ni = 0; ni < 4; ++ni)
            bfr[ni] = *(const bf16x8*)(const void*)(Bs + (wn + ni * 16 + lane15) * 32 + quad * 8);
        #pragma unroll
        for (int mi = 0; mi < 4; ++mi)
            #pragma unroll
            for (int ni = 0; ni < 4; ++ni)
                acc[mi][ni] = __builtin_amdgcn_mfma_f32_16x16x32_bf16(af[mi], bfr[ni], acc[mi][ni], 0, 0, 0);
    }

    #pragma unroll
    for (int mi = 0; mi < 4; ++mi) {
        const int rbase = m0 + wm + mi * 16 + quad * 4;
        #pragma unroll
        for (int ni = 0; ni < 4; ++ni) {
            const int c = n0 + wn + ni * 16 + lane15;
            #pragma unroll
            for (int p = 0; p < 4; ++p)
                Pz[(size_t)(rbase + p) * ldp + c] = acc[mi][ni][p];
        }
    }
}

// ---------------------------------------------------------------------------
// ckv reduce: sum 4 K-partials + bkva; cols<512 -> kvlat bf16;
// cols 512..575 -> RoPE -> kr bf16. One block per row s.
// ---------------------------------------------------------------------------
__global__ __launch_bounds__(256)
void ckv_reduce(const float* __restrict__ P, const float* __restrict__ bkva,
                __hip_bfloat16* __restrict__ kvlat, __hip_bfloat16* __restrict__ kr,
                const float* __restrict__ cosb, const float* __restrict__ sinb)
{
    const int s = blockIdx.x;
    const int t = threadIdx.x;
    const size_t zs = (size_t)S_LEN * 640;
    const float* row = P + (size_t)s * 640;

    for (int c = t; c < KV_RANK; c += 256) {
        float v = row[c] + row[zs + c] + row[2 * zs + c] + row[3 * zs + c] + bkva[c];
        kvlat[(size_t)s * KV_RANK + c] = __float2bfloat16(v);
    }
    if (t < 32) {
        const int d = t;
        float a = row[512 + d] + row[zs + 512 + d] + row[2 * zs + 512 + d] + row[3 * zs + 512 + d] + bkva[512 + d];
        float b = row[544 + d] + row[zs + 544 + d] + row[2 * zs + 544 + d] + row[3 * zs + 544 + d] + bkva[544 + d];
        const float c0 = cosb[s * ROPE_D + d],      c1 = cosb[s * ROPE_D + d + 32];
        const float s0 = sinb[s * ROPE_D + d],      s1 = sinb[s * ROPE_D + d + 32];
        kr[(size_t)s * ROPE_D + d]      = __float2bfloat16(a * c0 - b * s0);
        kr[(size_t)s * ROPE_D + d + 32] = __float2bfloat16(b * c1 + a * s1);
    }
}

// ---------------------------------------------------------------------------
// Wo reduce: out = P0 + P1 + P2 + P3 + bo  (fp32, float4).
// ---------------------------------------------------------------------------
__global__ __launch_bounds__(256)
void wo_reduce4(const float* __restrict__ P, const float* __restrict__ bo,
                float* __restrict__ out)
{
    const size_t i = (size_t)blockIdx.x * 256 + threadIdx.x;  // float4 index
    const size_t zs = (size_t)S_LEN * OUT_HID;
    float4 a = ((const float4*)P)[i];
    float4 b = ((const float4*)(P + zs))[i];
    float4 c = ((const float4*)(P + 2 * zs))[i];
    float4 d = ((const float4*)(P + 3 * zs))[i];
    const int col = (int)((i * 4) & (OUT_HID - 1));
    float4 bb = *(const float4*)(bo + col);
    float4 o;
    o.x = a.x + b.x + c.x + d.x + bb.x;
    o.y = a.y + b.y + c.y + d.y + bb.y;
    o.z = a.z + b.z + c.z + d.z + bb.z;
    o.w = a.w + b.w + c.w + d.w + bb.w;
    ((float4*)out)[i] = o;
}

// ---------------------------------------------------------------------------
// kv up-proj GEMM with split epilogue: kn [s][4096] + transposed V [4096][s].
// ---------------------------------------------------------------------------
__global__ __launch_bounds__(256)
void gemm_kv(const __hip_bfloat16* __restrict__ A,
             const __hip_bfloat16* __restrict__ Bt,
             __hip_bfloat16* __restrict__ kn,
             __hip_bfloat16* __restrict__ vt)
{
    __shared__ __hip_bfloat16 As[128 * 32];
    __shared__ __hip_bfloat16 Bs[128 * 32];

    const int t = threadIdx.x;
    const int w = t >> 6;
    const int L = t & 63;
    const int lane15 = L & 15, quad = L >> 4;
    const int wm = (w & 1) * 64, wn = (w >> 1) * 64;
    const int m0 = blockIdx.y * 128;
    const int n0 = blockIdx.x * 128;

    f32x4 acc[4][4];
    #pragma unroll
    for (int mi = 0; mi < 4; ++mi)
        #pragma unroll
        for (int ni = 0; ni < 4; ++ni)
            acc[mi][ni] = (f32x4){0.f, 0.f, 0.f, 0.f};

    for (int k0 = 0; k0 < KV_RANK; k0 += 32) {
        __syncthreads();
        #pragma unroll
        for (int i = 0; i < 2; ++i) {
            const int slot = w * 64 + i * 256 + L;
            const int base = (w * 64 + i * 256) * 8;
            async_load16(A  + (size_t)(m0 + (slot >> 2)) * KV_RANK + k0 + (slot & 3) * 8,
                         (void*)(As + base));
            async_load16(Bt + (size_t)(n0 + (slot >> 2)) * KV_RANK + k0 + (slot & 3) * 8,
                         (void*)(Bs + base));
        }
        __syncthreads();

        bf16x8 af[4], bfr[4];
        #pragma unroll
        for (int mi = 0; mi < 4; ++mi)
            af[mi] = *(const bf16x8*)(const void*)(As + (wm + mi * 16 + lane15) * 32 + quad * 8);
        #pragma unroll
        for (int ni = 0; ni < 4; ++ni)
            bfr[ni] = *(const bf16x8*)(const void*)(Bs + (wn + ni * 16 + lane15) * 32 + quad * 8);
        #pragma unroll
        for (int mi = 0; mi < 4; ++mi)
            #pragma unroll
            for (int ni = 0; ni < 4; ++ni)
                acc[mi][ni] = __builtin_amdgcn_mfma_f32_16x16x32_bf16(af[mi], bfr[ni], acc[mi][ni], 0, 0, 0);
    }

    #pragma unroll
    for (int mi = 0; mi < 4; ++mi) {
        const int rbase = m0 + wm + mi * 16 + quad * 4;
        #pragma unroll
        for (int ni = 0; ni < 4; ++ni) {
            const int c = n0 + wn + ni * 16 + lane15;
            const int h = c >> 8, d = c & 255;
            if (d < NOPE) {
                #pragma unroll
                for (int p = 0; p < 4; ++p)
                    kn[(size_t)(rbase + p) * KNW + h * NOPE + d] = __float2bfloat16(acc[mi][ni][p]);
            } else {
                ushort4 pk;
                __hip_bfloat16 b0 = __float2bfloat16(acc[mi][ni][0]);
                __hip_bfloat16 b1 = __float2bfloat16(acc[mi][ni][1]);
                __hip_bfloat16 b2 = __float2bfloat16(acc[mi][ni][2]);
                __hip_bfloat16 b3 = __float2bfloat16(acc[mi][ni][3]);
                pk.x = *(unsigned short*)&b0; pk.y = *(unsigned short*)&b1;
                pk.z = *(unsigned short*)&b2; pk.w = *(unsigned short*)&b3;
                *(ushort4*)(vt + (size_t)(h * VD + (d - NOPE)) * S_LEN + rbase) = pk;
            }
        }
    }
}

// ---------------------------------------------------------------------------
// MFMA sliding-window attention with sink, v2: K and V chunks staged into
// PADDED LDS via coalesced VGPR-roundtrip loads (fixes the 16-line-per-frag
// global gather of v1). q is pre-scaled by ATT_SCALE in gemm_q.
// Block = (32-query tile, head), 256 thr = 4 waves.
// LDS: S 21.25KB + P 10.5KB + stage 12.5KB = 44.3KB -> 3 blocks/CU.
// ---------------------------------------------------------------------------
#define SS 170     // fp32 S stride
#define SP 168     // bf16 P stride
#define KSTR 200   // staged K row stride (bf16), 400B, 16B-aligned
#define VSTR 40    // staged V row stride (bf16), 80B, 16B-aligned

__global__ __launch_bounds__(256)
void attn_mfma2(const __hip_bfloat16* __restrict__ q,
                const __hip_bfloat16* __restrict__ kn,
                const __hip_bfloat16* __restrict__ kr,
                const __hip_bfloat16* __restrict__ vt,
                const float* __restrict__ sinks,
                __hip_bfloat16* __restrict__ out)
{
    __shared__ float lds_s[32 * SS];
    __shared__ __hip_bfloat16 lds_p[32 * SP];
    __shared__ __hip_bfloat16 lds_kv[32 * KSTR];   // also used as [128][VSTR]

    const int h  = blockIdx.y;
    const int q0 = blockIdx.x * 32;
    const int t  = threadIdx.x;
    const int w  = t >> 6;
    const int L  = t & 63;
    const int lane15 = L & 15, quad = L >> 4;
    const int wm = (w & 1) * 16;
    const int wn = (w >> 1) * 16;

    int lo = q0 - SW + 1; if (lo < 0) lo = 0;
    const int cb = lo & ~31;
    const int nc = ((q0 - cb) >> 5) + 1;    // 1..5

    // Q fragments (pre-scaled), read once from global
    bf16x8 qf[6];
    {
        const __hip_bfloat16* qrow = q + (size_t)(q0 + wm + lane15) * NQK + h * QKD;
        #pragma unroll
        for (int kk = 0; kk < 6; ++kk)
            qf[kk] = *(const bf16x8*)(const void*)(qrow + kk * 32 + quad * 8);
    }

    // ---- QK^T per chunk: stage kn+kr (coalesced) -> LDS, then MFMA
    for (int cc = 0; cc < nc; ++cc) {
        const int c0 = cb + cc * 32;
        __syncthreads();   // previous chunk's staged K fully consumed
        #pragma unroll
        for (int e = t; e < 768; e += 256) {
            const int row = e / 24, slot = e % 24;
            const int j = c0 + row;
            const __hip_bfloat16* g = (slot < 16)
                ? kn + (size_t)j * KNW + h * NOPE + slot * 8
                : kr + (size_t)j * ROPE_D + (slot - 16) * 8;
            *(bf16x8*)(void*)(lds_kv + row * KSTR + slot * 8) = *(const bf16x8*)(const void*)g;
        }
        __syncthreads();

        f32x4 s = (f32x4){0.f, 0.f, 0.f, 0.f};
        #pragma unroll
        for (int kk = 0; kk < 6; ++kk) {
            bf16x8 bf = *(const bf16x8*)(const void*)(lds_kv + (wn + lane15) * KSTR + kk * 32 + quad * 8);
            s = __builtin_amdgcn_mfma_f32_16x16x32_bf16(qf[kk], bf, s, 0, 0, 0);
        }
        const int j = c0 + wn + lane15;
        #pragma unroll
        for (int p = 0; p < 4; ++p) {
            const int i = q0 + wm + quad * 4 + p;
            const bool ok = (j <= i) && (i - j < SW);
            lds_s[(wm + quad * 4 + p) * SS + cc * 32 + wn + lane15] = ok ? s[p] : NEG_INF;
        }
    }
    __syncthreads();

    // ---- softmax per row (8 threads/row), sink exact, 1/l folded into P
    {
        const int r = t >> 3, g = t & 7;
        const int ncols = nc * 32;
        const float sink = sinks[h];
        float mx = sink;
        for (int c = g; c < ncols; c += 8)
            mx = fmaxf(mx, lds_s[r * SS + c]);
        #pragma unroll
        for (int off = 1; off < 8; off <<= 1)
            mx = fmaxf(mx, __shfl_xor(mx, off));
        float sum = 0.f;
        for (int c = g; c < ncols; c += 8) {
            float e = __expf(lds_s[r * SS + c] - mx);
            lds_s[r * SS + c] = e;
            sum += e;
        }
        #pragma unroll
        for (int off = 1; off < 8; off <<= 1)
            sum += __shfl_xor(sum, off);
        const float inv = 1.0f / (sum + __expf(sink - mx));
        for (int c = g; c < ncols; c += 8)
            lds_p[r * SP + c] = __float2bfloat16(lds_s[r * SS + c] * inv);
    }

    // ---- PV per chunk: stage vt chunk (coalesced) -> LDS, then MFMA
    f32x4 oacc[4];
    #pragma unroll
    for (int ni = 0; ni < 4; ++ni) oacc[ni] = (f32x4){0.f, 0.f, 0.f, 0.f};

    for (int cc = 0; cc < nc; ++cc) {
        const int c0 = cb + cc * 32;
        __syncthreads();   // staged K (cc==0) or previous V chunk consumed; P ready
        #pragma unroll
        for (int e = t; e < 512; e += 256) {
            const int row = e >> 2, slot = e & 3;
            *(bf16x8*)(void*)(lds_kv + row * VSTR + slot * 8) =
                *(const bf16x8*)(const void*)(vt + (size_t)(h * VD + row) * S_LEN + c0 + slot * 8);
        }
        __syncthreads();

        bf16x8 ap = *(const bf16x8*)(const void*)(lds_p + (wm + lane15) * SP + cc * 32 + quad * 8);
        #pragma unroll
        for (int ni = 0; ni < 4; ++ni) {
            bf16x8 bv = *(const bf16x8*)(const void*)(lds_kv + ((w >> 1) * 64 + ni * 16 + lane15) * VSTR + quad * 8);
            oacc[ni] = __builtin_amdgcn_mfma_f32_16x16x32_bf16(ap, bv, oacc[ni], 0, 0, 0);
        }
    }

    #pragma unroll
    for (int ni = 0; ni < 4; ++ni) {
        const int col = h * VD + (w >> 1) * 64 + ni * 16 + lane15;
        #pragma unroll
        for (int p = 0; p < 4; ++p) {
            const int row = q0 + wm + quad * 4 + p;
            out[(size_t)row * (NH * VD) + col] = __float2bfloat16(oacc[ni][p]);
        }
    }
}

// ---------------------------------------------------------------------------
extern "C" void kernel_launch(void* const* d_in, const int* in_sizes, int n_in,
                              void* d_out, int out_size, void* d_ws, size_t ws_size,
                              hipStream_t stream) {
    const float* hidden = (const float*)d_in[0];
    const float* cosb   = (const float*)d_in[1];
    const float* sinb   = (const float*)d_in[2];
    const float* Wq     = (const float*)d_in[3];
    const float* bq     = (const float*)d_in[4];
    const float* Wkva   = (const float*)d_in[5];
    const float* bkva   = (const float*)d_in[6];
    const float* Wkvb   = (const float*)d_in[7];
    const float* Wo     = (const float*)d_in[8];
    const float* bo     = (const float*)d_in[9];
    const float* sinks  = (const float*)d_in[10];
    float* out = (float*)d_out;

    // workspace, 139.0 MB. Aliases:
    //   ckvP (21.0 MB fp32) <- WqT (25.2 MB, dead after gemm_q)
    //   WoP  (67.1 MB fp32) <- [q_bf..WkvbT] (69.7 MB, all dead after attn)
    uint8_t* p = (uint8_t*)d_ws;
    __hip_bfloat16* attn_bf = (__hip_bfloat16*)p; p += (size_t)S_LEN * NH * VD * 2;   // 16.78 MB
    __hip_bfloat16* WoT     = (__hip_bfloat16*)p; p += (size_t)OUT_HID * (NH*VD) * 2; // 16.78 MB
    __hip_bfloat16* q_bf    = (__hip_bfloat16*)p; p += (size_t)S_LEN * NQK * 2;       // 25.17 MB
    __hip_bfloat16* hid_bf  = (__hip_bfloat16*)p; p += (size_t)S_LEN * HID_DIM * 2;   //  8.39 MB
    __hip_bfloat16* WqT     = (__hip_bfloat16*)p; p += (size_t)NQK * HID_DIM * 2;     // 25.17 MB
    __hip_bfloat16* WkvaT   = (__hip_bfloat16*)p; p += (size_t)640 * HID_DIM * 2;     //  2.62 MB
    __hip_bfloat16* WkvbT   = (__hip_bfloat16*)p; p += (size_t)KVN * KV_RANK * 2;     //  8.39 MB
    __hip_bfloat16* kn_bf   = (__hip_bfloat16*)p; p += (size_t)S_LEN * KNW * 2;       // 16.78 MB
    __hip_bfloat16* vt_bf   = (__hip_bfloat16*)p; p += (size_t)S_LEN * NH * VD * 2;   // 16.78 MB
    __hip_bfloat16* kr_bf   = (__hip_bfloat16*)p; p += (size_t)S_LEN * ROPE_D * 2;    //  0.26 MB
    __hip_bfloat16* kvlat   = (__hip_bfloat16*)p; p += (size_t)S_LEN * KV_RANK * 2;   //  2.10 MB
    float* ckvP = (float*)WqT;     // after gemm_q
    float* WoP  = (float*)q_bf;    // after attn

    // 1. conversions (hidden cvt + 4 weight transposes, 64x64 tiles)
    prep<<<10528, 256, 0, stream>>>(hidden, hid_bf, Wq, WqT, Wkva, WkvaT,
                                    Wkvb, WkvbT, Wo, WoT);

    // 2. q = (hidden @ Wq + bq), RoPE + ATT_SCALE fused
    gemm_q<<<dim3(NQK / 128, S_LEN / 128), 256, 0, stream>>>(
        hid_bf, WqT, bq, cosb, sinb, q_bf);

    // 3. ckv partials: split-K x4 (320 blocks)   [clobbers WqT]
    gemm_partial<<<dim3(5, S_LEN / 128, 4), 256, 0, stream>>>(
        hid_bf, HID_DIM, WkvaT, HID_DIM, ckvP, 640, (size_t)S_LEN * 640, 512);

    // 4. reduce + bias + kvlat bf16 + k-RoPE
    ckv_reduce<<<S_LEN, 256, 0, stream>>>(ckvP, bkva, kvlat, kr_bf, cosb, sinb);

    // 5. kv up-proj: kn + transposed V
    gemm_kv<<<dim3(KVN / 128, S_LEN / 128), 256, 0, stream>>>(
        kvlat, WkvbT, kn_bf, vt_bf);

    // 6. attention (MFMA, LDS-staged K/V)
    attn_mfma2<<<dim3(S_LEN / 32, NH), 256, 0, stream>>>(
        q_bf, kn_bf, kr_bf, vt_bf, sinks, attn_bf);

    // 7. Wo partials: split-K x4 (1024 blocks)   [clobbers q_bf..WkvbT]
    gemm_partial<<<dim3(OUT_HID / 128, S_LEN / 128, 4), 256, 0, stream>>>(
        attn_bf, NH * VD, WoT, NH * VD, WoP, OUT_HID, (size_t)S_LEN * OUT_HID, 1024);

    // 8. out = P0+P1+P2+P3 + bo
    wo_reduce4<<<(S_LEN * OUT_HID / 4) / 256, 256, 0, stream>>>(WoP, bo, out);
}